// Round 19
// baseline (270.953 us; speedup 1.0000x reference)
//
#include <hip/hip_runtime.h>
#include <math.h>

#define N_NODES 50000
#define N_EDGES 800000
#define FDIM 128
#define NH 8
#define NC 32
#define D1 256      // NH*NC
#define NCLS 16
#define NGRP 64
#define NEG 0.2f
#define E_TOT (N_EDGES + N_NODES)
#define NB_N 196        // (N_NODES+255)/256
#define G1_BLOCKS 782   // (N_NODES+63)/64
#define E_CHUNK 4096
#define NCHUNK 196      // ceil(800000/4096)
#define NBIN 196        // ceil(50000/256)

typedef __attribute__((ext_vector_type(4))) unsigned short u16x4;
typedef __attribute__((ext_vector_type(8))) unsigned short u16x8;
typedef __attribute__((ext_vector_type(8))) short short8;
typedef __attribute__((ext_vector_type(4))) float f32x4;

static __device__ __forceinline__ float bf2f(unsigned short u) {
    return __uint_as_float(((unsigned int)u) << 16);
}
static __device__ __forceinline__ unsigned short f2bf(float f) {
    unsigned int b = __float_as_uint(f);
    return (unsigned short)((b + 0x7FFFu + ((b >> 16) & 1u)) >> 16);
}

// ---- init (pool zero + W1 pack) FUSED with per-chunk bin histogram -----------
__global__ __launch_bounds__(256) void k_init(
    const float* __restrict__ W1, unsigned short* __restrict__ w1p,
    float* __restrict__ poolS, float* __restrict__ poolC,
    const int* __restrict__ ei, int* __restrict__ binmat) {
    __shared__ int h[NBIN];
    int c = blockIdx.x;
    for (int b = threadIdx.x; b < NBIN; b += 256) h[b] = 0;
    __syncthreads();
    int e0 = c * E_CHUNK;
    int e1 = e0 + E_CHUNK; if (e1 > N_EDGES) e1 = N_EDGES;
    for (int e = e0 + threadIdx.x; e < e1; e += 256)
        atomicAdd(&h[ei[N_EDGES + e] >> 8], 1);
    int i = blockIdx.x * 256 + threadIdx.x;
    if (i < NGRP * NCLS) poolS[i] = 0.f;
    if (i < NGRP) poolC[i] = 0.f;
    if (i < FDIM * D1) {
        int ks = i >> 13;
        int r = i & 8191;
        int nt2 = r >> 9;
        int r2 = r & 511;
        int lane = r2 >> 3, e = r2 & 7;
        int k = ks * 32 + (lane >> 4) * 8 + e;
        int col = nt2 * 16 + (lane & 15);
        w1p[i] = f2bf(W1[k * D1 + col]);
    }
    __syncthreads();
    for (int b = threadIdx.x; b < NBIN; b += 256) binmat[b * NCHUNK + c] = h[b];
}

// ---- per-bin row scan: binmat[b][*] -> exclusive within-row prefix + total ---
__global__ __launch_bounds__(256) void k_binprescan(int* __restrict__ binmat,
                                                    int* __restrict__ binTot) {
    __shared__ int sh[256];
    int b = blockIdx.x, t = threadIdx.x;
    int v = (t < NCHUNK) ? binmat[b * NCHUNK + t] : 0;
    sh[t] = v;
    __syncthreads();
    for (int d = 1; d < 256; d <<= 1) {
        int tv = (t >= d) ? sh[t - d] : 0;
        __syncthreads();
        sh[t] += tv;
        __syncthreads();
    }
    if (t < NCHUNK) binmat[b * NCHUNK + t] = sh[t] - v;   // exclusive in-row
    if (t == 255) binTot[b] = sh[255];
}

// -- GEMM1 via MFMA bf16 + fused al1 (COLUMN layout [H][N]); tail = binscatter -
__global__ __launch_bounds__(256) void k_gemm1m(
    const float* __restrict__ x, const unsigned short* __restrict__ w1p,
    const float* __restrict__ a1s, const float* __restrict__ a1d,
    unsigned short* __restrict__ xp1b, float* __restrict__ al1s,
    float* __restrict__ al1d, const int* __restrict__ ei,
    const int* __restrict__ offs, const int* __restrict__ binTot,
    int* __restrict__ binned) {
    __shared__ int cur[NBIN];
    __shared__ int sb[256];
    if (blockIdx.x >= G1_BLOCKS) {
        int c = blockIdx.x - G1_BLOCKS;
        int t = threadIdx.x;
        int v = (t < NBIN) ? binTot[t] : 0;
        sb[t] = v;
        __syncthreads();
        for (int d = 1; d < 256; d <<= 1) {
            int tv = (t >= d) ? sb[t - d] : 0;
            __syncthreads();
            sb[t] += tv;
            __syncthreads();
        }
        if (t < NBIN) cur[t] = (sb[t] - v) + offs[t * NCHUNK + c];
        __syncthreads();
        int e0 = c * E_CHUNK;
        int e1 = e0 + E_CHUNK; if (e1 > N_EDGES) e1 = N_EDGES;
        for (int e = e0 + t; e < e1; e += 256) {
            int s = ei[e], d = ei[N_EDGES + e];
            int pos = atomicAdd(&cur[d >> 8], 1);
            binned[pos] = s | ((d & 255) << 16);   // src < 65536
        }
        return;
    }
    const int l = threadIdx.x & 63;
    const int wid = threadIdx.x >> 6;
    const int wr = wid >> 1, wc = wid & 1;
    const int l15 = l & 15, l4 = l >> 4;
    const int base = blockIdx.x * 64;
    const int r0 = base + wr * 32;

    f32x4 acc[2][8] = {};
#pragma unroll
    for (int ks = 0; ks < 4; ++ks) {
        const int kk = ks * 32 + l4 * 8;
        short8 af[2];
#pragma unroll
        for (int rt = 0; rt < 2; ++rt) {
            int row = r0 + rt * 16 + l15;
            float4 v0 = make_float4(0.f, 0.f, 0.f, 0.f), v1 = v0;
            if (row < N_NODES) {
                const float* xr = x + (size_t)row * FDIM + kk;
                v0 = *(const float4*)xr;
                v1 = *(const float4*)(xr + 4);
            }
            short8 a;
            a[0] = (short)f2bf(v0.x); a[1] = (short)f2bf(v0.y);
            a[2] = (short)f2bf(v0.z); a[3] = (short)f2bf(v0.w);
            a[4] = (short)f2bf(v1.x); a[5] = (short)f2bf(v1.y);
            a[6] = (short)f2bf(v1.z); a[7] = (short)f2bf(v1.w);
            af[rt] = a;
        }
#pragma unroll
        for (int nt = 0; nt < 8; ++nt) {
            int nt2 = wc * 8 + nt;
            short8 bf_ = *(const short8*)&w1p[(size_t)((ks * 16 + nt2) * 64 + l) * 8];
            acc[0][nt] = __builtin_amdgcn_mfma_f32_16x16x32_bf16(af[0], bf_, acc[0][nt], 0, 0, 0);
            acc[1][nt] = __builtin_amdgcn_mfma_f32_16x16x32_bf16(af[1], bf_, acc[1][nt], 0, 0, 0);
        }
    }
#pragma unroll
    for (int rt = 0; rt < 2; ++rt) {
        int rbase = r0 + rt * 16 + l4 * 4;
#pragma unroll
        for (int nt = 0; nt < 8; ++nt) {
            int col = wc * 128 + nt * 16 + l15;
            f32x4 c = acc[rt][nt];
#pragma unroll
            for (int r = 0; r < 4; ++r) {
                int row = rbase + r;
                if (row < N_NODES) xp1b[(size_t)row * D1 + col] = f2bf(c[r]);
            }
        }
    }
#pragma unroll
    for (int hl = 0; hl < 4; ++hl) {
        int hg = wc * 4 + hl;
        float as0 = a1s[hg * NC + l15], as1 = a1s[hg * NC + 16 + l15];
        float ad0 = a1d[hg * NC + l15], ad1 = a1d[hg * NC + 16 + l15];
#pragma unroll
        for (int rt = 0; rt < 2; ++rt) {
            f32x4 c0 = acc[rt][2 * hl], c1 = acc[rt][2 * hl + 1];
#pragma unroll
            for (int r = 0; r < 4; ++r) {
                float ss = c0[r] * as0 + c1[r] * as1;
                float dd = c0[r] * ad0 + c1[r] * ad1;
#pragma unroll
                for (int msk = 1; msk < 16; msk <<= 1) {
                    ss += __shfl_xor(ss, msk);
                    dd += __shfl_xor(dd, msk);
                }
                int row = r0 + rt * 16 + l4 * 4 + r;
                if (l15 == 0 && row < N_NODES) {
                    al1s[hg * N_NODES + row] = ss;   // COLUMN layout [H][N]
                    al1d[hg * N_NODES + row] = dd;
                }
            }
        }
    }
}

// ---- per-bin CSR finalize (scan binTot inline) -------------------------------
__global__ __launch_bounds__(256) void k_bincsr(const int* __restrict__ binTot,
                                                const int* __restrict__ binned,
                                                int* __restrict__ rowptr,
                                                int* __restrict__ cnt,
                                                int* __restrict__ esrc) {
    __shared__ int sh[256];
    __shared__ int lcnt[256];
    __shared__ int lcur[256];
    int b = blockIdx.x;
    int t = threadIdx.x;
    int v = (t < NBIN) ? binTot[t] : 0;
    sh[t] = v;
    __syncthreads();
    for (int d = 1; d < 256; d <<= 1) {
        int tv = (t >= d) ? sh[t - d] : 0;
        __syncthreads();
        sh[t] += tv;
        __syncthreads();
    }
    int estart = (b == 0) ? 0 : sh[b - 1];
    int eend = sh[b];
    __syncthreads();
    int nbase = b * 256;
    int nin = N_NODES - nbase; if (nin > 256) nin = 256;
    lcnt[t] = 0;
    __syncthreads();
    for (int e = estart + t; e < eend; e += 256)
        atomicAdd(&lcnt[(binned[e] >> 16) & 255], 1);
    __syncthreads();
    int myc = lcnt[t] + (t < nin ? 1 : 0);   // + self loop
    sh[t] = myc;
    __syncthreads();
    for (int d = 1; d < 256; d <<= 1) {
        int tv = (t >= d) ? sh[t - d] : 0;
        __syncthreads();
        sh[t] += tv;
        __syncthreads();
    }
    int excl = sh[t] - myc;
    int outbase = estart + nbase;            // earlier bins' self-loops = nbase
    int rp = outbase + excl;
    if (t < nin) {
        rowptr[nbase + t] = rp;
        cnt[nbase + t] = myc;
        esrc[rp] = nbase + t;                // self-loop in slot 0
    }
    lcur[t] = rp + (t < nin ? 1 : 0);
    __syncthreads();
    for (int e = estart + t; e < eend; e += 256) {
        int vv = binned[e];
        int pos = atomicAdd(&lcur[(vv >> 16) & 255], 1);
        esrc[pos] = vv & 0xFFFF;
    }
}

// -- attention layer 1, XCD-SHARDED by head: block's head = blockIdx&7 --------
// Dispatch round-robins blocks across the 8 XCDs, so XCD k only gathers head
// k's 32-channel slice (3.2 MB, fits its private 4 MB L2) + 200 KB logit col.
__global__ __launch_bounds__(256) void k_att1s(
    const unsigned short* __restrict__ xp1b, const float* __restrict__ al1s,
    const float* __restrict__ al1d, const float* __restrict__ b1,
    const int* __restrict__ rowptr, const int* __restrict__ cnt,
    const int* __restrict__ esrc, unsigned short* __restrict__ h1b) {
    __shared__ int s_src[4][64];
    __shared__ float s_alpha[4][64];
    int wv = threadIdx.x >> 6;
    int lane = threadIdx.x & 63;
    int hh = blockIdx.x & 7;                   // head == XCD slot
    int n = (blockIdx.x >> 3) * 4 + wv;        // 12500*8 blocks cover 50000 nodes
    int start = rowptr[n];
    int deg = cnt[n];
    int dcap = deg < 64 ? deg : 64;
    int dpad = (dcap + 7) & ~7;
    const float* alsc = al1s + (size_t)hh * N_NODES;
    float ald = al1d[(size_t)hh * N_NODES + n];
    // pass 1: lane j owns edge j (deg<=64 common case); stats via wave reduce
    int s0 = n;
    float v = -1e30f;
    if (lane < dcap) {
        s0 = esrc[start + lane];
        float t = alsc[s0] + ald;
        v = fmaxf(t, NEG * t);
    }
    s_src[wv][lane] = (lane < dcap) ? s0 : n;  // pad with self (hot line)
    float m = v;
    if (deg > 64) {
        for (int j = 64 + lane; j < deg; j += 64) {
            float t = alsc[esrc[start + j]] + ald;
            m = fmaxf(m, fmaxf(t, NEG * t));
        }
    }
    for (int msk = 1; msk < 64; msk <<= 1) m = fmaxf(m, __shfl_xor(m, msk));
    float a = (lane < dcap) ? __expf(v - m) : 0.f;
    s_alpha[wv][lane] = a;                     // unnormalized; pad = 0
    float den = a;
    if (deg > 64) {
        for (int j = 64 + lane; j < deg; j += 64) {
            float t = alsc[esrc[start + j]] + ald;
            t = fmaxf(t, NEG * t);
            den += __expf(t - m);
        }
    }
    for (int msk = 1; msk < 64; msk <<= 1) den += __shfl_xor(den, msk);
    float rd = 1.f / den;
    // pass 2: 2 edges x 32 channels; 8 edges per unrolled batch; mask-free
    int e2 = lane >> 5, c = lane & 31;
    const int cbb = (hh * 32 + c) * 2;         // byte offset within 512B row
    float acc = 0.f;
    for (int j0 = 0; j0 < dpad; j0 += 8) {
        float aw[4]; int off[4];
#pragma unroll
        for (int k = 0; k < 4; ++k) {
            int e = j0 + e2 + 2 * k;
            int s = s_src[wv][e];
            aw[k] = s_alpha[wv][e];
            off[k] = (s << 9) + cbb;
        }
#pragma unroll
        for (int k = 0; k < 4; ++k) {
            unsigned short xv = *(const unsigned short*)((const char*)xp1b + off[k]);
            acc = fmaf(aw[k], bf2f(xv), acc);
        }
    }
    if (deg > 64) {
        for (int j = 64 + e2; j < deg; j += 2) {
            int s = esrc[start + j];
            float t = alsc[s] + ald;
            t = fmaxf(t, NEG * t);
            float al = __expf(t - m);
            unsigned short xv = *(const unsigned short*)((const char*)xp1b + (s << 9) + cbb);
            acc = fmaf(al, bf2f(xv), acc);
        }
    }
    acc += __shfl_xor(acc, 32);
    if (e2 == 0) {                             // lanes 0-31: coalesced 64B store
        float hv = fmaf(acc, rd, b1[hh * NC + c]);
        hv = hv > 0.f ? hv : expm1f(hv);
        h1b[(size_t)n * D1 + hh * NC + c] = f2bf(hv);
    }
}

// ---- GEMM2 (bf16 h1 in, broadcast W2) -> bf16 xp2 + al2 logits ---------------
__global__ __launch_bounds__(256) void k_gemm2(
    const unsigned short* __restrict__ h1b, const float* __restrict__ W2,
    const float* __restrict__ a2s, const float* __restrict__ a2d,
    unsigned short* __restrict__ xp2b, float* __restrict__ al2s,
    float* __restrict__ al2d) {
    __shared__ float w2s[D1 * NCLS];
    for (int i = threadIdx.x; i < D1 * NCLS; i += 256) w2s[i] = W2[i];
    __syncthreads();
    int n = blockIdx.x * 256 + threadIdx.x;
    if (n >= N_NODES) return;
    float4 acc[4];
#pragma unroll
    for (int q = 0; q < 4; ++q) acc[q] = make_float4(0.f, 0.f, 0.f, 0.f);
    const unsigned short* hr = h1b + (size_t)n * D1;
    for (int k0 = 0; k0 < D1; k0 += 8) {
        u16x8 hv = *(const u16x8*)(hr + k0);
#pragma unroll
        for (int j = 0; j < 8; ++j) {
            float hx = bf2f(hv[j]);
#pragma unroll
            for (int q = 0; q < 4; ++q) {
                float4 w = *(const float4*)(&w2s[(k0 + j) * NCLS + q * 4]);
                acc[q].x = fmaf(hx, w.x, acc[q].x);
                acc[q].y = fmaf(hx, w.y, acc[q].y);
                acc[q].z = fmaf(hx, w.z, acc[q].z);
                acc[q].w = fmaf(hx, w.w, acc[q].w);
            }
        }
    }
    float ss = 0.f, dd = 0.f;
    u16x8 pk0, pk1;
#pragma unroll
    for (int q = 0; q < 4; ++q) {
        float4 s4 = *(const float4*)(a2s + q * 4);
        float4 d4 = *(const float4*)(a2d + q * 4);
        ss += acc[q].x * s4.x + acc[q].y * s4.y + acc[q].z * s4.z + acc[q].w * s4.w;
        dd += acc[q].x * d4.x + acc[q].y * d4.y + acc[q].z * d4.z + acc[q].w * d4.w;
    }
    pk0[0] = f2bf(acc[0].x); pk0[1] = f2bf(acc[0].y);
    pk0[2] = f2bf(acc[0].z); pk0[3] = f2bf(acc[0].w);
    pk0[4] = f2bf(acc[1].x); pk0[5] = f2bf(acc[1].y);
    pk0[6] = f2bf(acc[1].z); pk0[7] = f2bf(acc[1].w);
    pk1[0] = f2bf(acc[2].x); pk1[1] = f2bf(acc[2].y);
    pk1[2] = f2bf(acc[2].z); pk1[3] = f2bf(acc[2].w);
    pk1[4] = f2bf(acc[3].x); pk1[5] = f2bf(acc[3].y);
    pk1[6] = f2bf(acc[3].z); pk1[7] = f2bf(acc[3].w);
    *(u16x8*)(xp2b + (size_t)n * NCLS) = pk0;
    *(u16x8*)(xp2b + (size_t)n * NCLS + 8) = pk1;
    al2s[n] = ss;
    al2d[n] = dd;
}

// -------- attention layer 2 (bf16 xp2 gather, mask-free padded pass 2) --------
__global__ __launch_bounds__(256) void k_att2(
    const unsigned short* __restrict__ xp2b, const float* __restrict__ al2s,
    const float* __restrict__ al2d, const float* __restrict__ b2,
    const int* __restrict__ rowptr, const int* __restrict__ cnt,
    const int* __restrict__ esrc, float* __restrict__ out2) {
    __shared__ int s_src[4][64];
    __shared__ float s_a[4][64];
    int wave = threadIdx.x >> 6;
    int lane = threadIdx.x & 63;
    int n = blockIdx.x * 4 + wave;
    int start = rowptr[n];
    int deg = cnt[n];
    int dcap = deg < 64 ? deg : 64;
    int dpad = (dcap + 7) & ~7;
    for (int j = lane; j < dpad; j += 64)
        s_src[wave][j] = (j < dcap) ? esrc[start + j] : n;
    if (lane < dpad - dcap) s_a[wave][dcap + lane] = 0.f;
    float ald = al2d[n];
    float m = -1e30f;
    for (int j = lane; j < dcap; j += 64) {
        int s = s_src[wave][j];
        float v = al2s[s] + ald;
        v = fmaxf(v, NEG * v);
        s_a[wave][j] = v;
        m = fmaxf(m, v);
    }
    if (deg > 64) {
        for (int j = 64 + lane; j < deg; j += 64) {
            float v = al2s[esrc[start + j]] + ald;
            m = fmaxf(m, fmaxf(v, NEG * v));
        }
    }
    for (int msk = 1; msk < 64; msk <<= 1) m = fmaxf(m, __shfl_xor(m, msk));
    float den = 0.f;
    for (int j = lane; j < dcap; j += 64) {
        float e = __expf(s_a[wave][j] - m);
        s_a[wave][j] = e;
        den += e;
    }
    if (deg > 64) {
        for (int j = 64 + lane; j < deg; j += 64) {
            float v = al2s[esrc[start + j]] + ald;
            v = fmaxf(v, NEG * v);
            den += __expf(v - m);
        }
    }
    for (int msk = 1; msk < 64; msk <<= 1) den += __shfl_xor(den, msk);
    float rden = 1.f / den;
    int c = lane & 15;
    int eg = lane >> 4;                   // 4 edge slots x 16 channels
    float acc = 0.f;
    for (int j0 = 0; j0 < dpad; j0 += 8) {
#pragma unroll
        for (int k = 0; k < 2; ++k) {
            int e = j0 + eg + 4 * k;
            float aw = s_a[wave][e];
            int s = s_src[wave][e];
            acc = fmaf(aw, bf2f(xp2b[(size_t)s * NCLS + c]), acc);
        }
    }
    if (deg > 64) {
        for (int j = 64 + eg; j < deg; j += 4) {
            int s = esrc[start + j];
            float v = al2s[s] + ald;
            v = fmaxf(v, NEG * v);
            acc += __expf(v - m) * bf2f(xp2b[(size_t)s * NCLS + c]);
        }
    }
    acc += __shfl_xor(acc, 16);
    acc += __shfl_xor(acc, 32);
    if (lane < 16) out2[(size_t)n * NCLS + lane] = acc * rden + b2[lane];
}

// ---------------- pooling (LDS pre-aggregation, sorted batch) -----------------
__global__ __launch_bounds__(256) void k_pool(
    const float* __restrict__ out2, const int* __restrict__ batch,
    float* __restrict__ poolS, float* __restrict__ poolC) {
    __shared__ float sacc[NGRP * NCLS];
    __shared__ float scnt[NGRP];
    for (int i = threadIdx.x; i < NGRP * NCLS; i += 256) sacc[i] = 0.f;
    if (threadIdx.x < NGRP) scnt[threadIdx.x] = 0.f;
    __syncthreads();
    int n = blockIdx.x * 256 + threadIdx.x;
    if (n < N_NODES) {
        int g = batch[n];
        atomicAdd(&scnt[g], 1.f);
#pragma unroll
        for (int q = 0; q < 4; ++q) {
            float4 v = *(const float4*)(out2 + (size_t)n * NCLS + q * 4);
            atomicAdd(&sacc[g * NCLS + q * 4 + 0], v.x);
            atomicAdd(&sacc[g * NCLS + q * 4 + 1], v.y);
            atomicAdd(&sacc[g * NCLS + q * 4 + 2], v.z);
            atomicAdd(&sacc[g * NCLS + q * 4 + 3], v.w);
        }
    }
    __syncthreads();
    for (int i = threadIdx.x; i < NGRP * NCLS; i += 256)
        if (sacc[i] != 0.f) atomicAdd(&poolS[i], sacc[i]);
    if (threadIdx.x < NGRP && scnt[threadIdx.x] != 0.f)
        atomicAdd(&poolC[threadIdx.x], scnt[threadIdx.x]);
}

__global__ void k_final(const float* __restrict__ poolS,
                        const float* __restrict__ poolC, float* __restrict__ out) {
    int g = threadIdx.x;
    if (g >= NGRP) return;
    float inv = 1.f / fmaxf(poolC[g], 1.f);
    float v[NCLS];
    float m = -1e30f;
#pragma unroll
    for (int c = 0; c < NCLS; ++c) {
        v[c] = poolS[g * NCLS + c] * inv;
        m = fmaxf(m, v[c]);
    }
    float s = 0.f;
#pragma unroll
    for (int c = 0; c < NCLS; ++c) s += expf(v[c] - m);
    float lse = m + logf(s);
#pragma unroll
    for (int c = 0; c < NCLS; ++c) out[g * NCLS + c] = v[c] - lse;
}

extern "C" void kernel_launch(void* const* d_in, const int* in_sizes, int n_in,
                              void* d_out, int out_size, void* d_ws, size_t ws_size,
                              hipStream_t stream) {
    const float* x    = (const float*)d_in[0];
    const int*   ei   = (const int*)d_in[1];
    const int*   batch = (const int*)d_in[2];
    const float* W1   = (const float*)d_in[3];
    const float* a1s  = (const float*)d_in[4];
    const float* a1d  = (const float*)d_in[5];
    const float* b1   = (const float*)d_in[6];
    const float* W2   = (const float*)d_in[7];
    const float* a2s  = (const float*)d_in[8];
    const float* a2d  = (const float*)d_in[9];
    const float* b2   = (const float*)d_in[10];
    float* out = (float*)d_out;

    float* f = (float*)d_ws;
    float* al1s_ = f;  f += (size_t)N_NODES * NH;   // [H][N] column layout
    float* al1d_ = f;  f += (size_t)N_NODES * NH;
    float* al2s_ = f;  f += N_NODES;
    float* al2d_ = f;  f += N_NODES;
    float* out2  = f;  f += (size_t)N_NODES * NCLS;
    float* poolS = f;  f += NGRP * NCLS;
    float* poolC = f;  f += NGRP;
    unsigned short* xp1b = (unsigned short*)f;
    unsigned short* h1b  = xp1b + (size_t)N_NODES * D1;
    unsigned short* xp2b = h1b + (size_t)N_NODES * D1;
    unsigned short* w1p  = xp2b + (size_t)N_NODES * NCLS;
    int* binmat  = (int*)(w1p + FDIM * D1);
    int* binTot  = binmat + NBIN * NCHUNK;
    int* binned  = binTot + NBIN;
    int* rowptr  = binned + N_EDGES;
    int* cnt     = rowptr + N_NODES;
    int* esrc    = cnt + N_NODES;

    k_init<<<NB_N, 256, 0, stream>>>(W1, w1p, poolS, poolC, ei, binmat);
    k_binprescan<<<NBIN, 256, 0, stream>>>(binmat, binTot);
    k_gemm1m<<<G1_BLOCKS + NCHUNK, 256, 0, stream>>>(x, w1p, a1s, a1d, xp1b,
                                                     al1s_, al1d_, ei, binmat,
                                                     binTot, binned);
    k_bincsr<<<NBIN, 256, 0, stream>>>(binTot, binned, rowptr, cnt, esrc);
    k_att1s<<<(N_NODES / 4) * 8, 256, 0, stream>>>(xp1b, al1s_, al1d_, b1,
                                                   rowptr, cnt, esrc, h1b);
    k_gemm2<<<NB_N, 256, 0, stream>>>(h1b, W2, a2s, a2d, xp2b, al2s_, al2d_);
    k_att2<<<N_NODES / 4, 256, 0, stream>>>(xp2b, al2s_, al2d_, b2, rowptr, cnt, esrc, out2);
    k_pool<<<NB_N, 256, 0, stream>>>(out2, batch, poolS, poolC);
    k_final<<<1, 64, 0, stream>>>(poolS, poolC, out);
}

// Round 20
// 170.417 us; speedup vs baseline: 1.5899x; 1.5899x over previous
//
#include <hip/hip_runtime.h>
#include <math.h>

#define N_NODES 50000
#define N_EDGES 800000
#define FDIM 128
#define NH 8
#define NC 32
#define D1 256      // NH*NC
#define NCLS 16
#define NGRP 64
#define NEG 0.2f
#define E_TOT (N_EDGES + N_NODES)
#define NB_N 196        // (N_NODES+255)/256
#define G1_BLOCKS 782   // (N_NODES+63)/64
#define E_CHUNK 4096
#define NCHUNK 196      // ceil(800000/4096)
#define NBIN 196        // ceil(50000/256)

typedef __attribute__((ext_vector_type(4))) unsigned short u16x4;
typedef __attribute__((ext_vector_type(8))) unsigned short u16x8;
typedef __attribute__((ext_vector_type(8))) short short8;
typedef __attribute__((ext_vector_type(4))) float f32x4;

static __device__ __forceinline__ float bf2f(unsigned short u) {
    return __uint_as_float(((unsigned int)u) << 16);
}
static __device__ __forceinline__ unsigned short f2bf(float f) {
    unsigned int b = __float_as_uint(f);
    return (unsigned short)((b + 0x7FFFu + ((b >> 16) & 1u)) >> 16);
}

// ---- init (pool zero + W1 pack) FUSED with per-chunk bin histogram -----------
__global__ __launch_bounds__(256) void k_init(
    const float* __restrict__ W1, unsigned short* __restrict__ w1p,
    float* __restrict__ poolS, float* __restrict__ poolC,
    const int* __restrict__ ei, int* __restrict__ binmat) {
    __shared__ int h[NBIN];
    int c = blockIdx.x;
    for (int b = threadIdx.x; b < NBIN; b += 256) h[b] = 0;
    __syncthreads();
    int e0 = c * E_CHUNK;
    int e1 = e0 + E_CHUNK; if (e1 > N_EDGES) e1 = N_EDGES;
    for (int e = e0 + threadIdx.x; e < e1; e += 256)
        atomicAdd(&h[ei[N_EDGES + e] >> 8], 1);
    // independent init work while histogram atomics settle
    int i = blockIdx.x * 256 + threadIdx.x;
    if (i < NGRP * NCLS) poolS[i] = 0.f;
    if (i < NGRP) poolC[i] = 0.f;
    if (i < FDIM * D1) {
        int ks = i >> 13;
        int r = i & 8191;
        int nt2 = r >> 9;
        int r2 = r & 511;
        int lane = r2 >> 3, e = r2 & 7;
        int k = ks * 32 + (lane >> 4) * 8 + e;
        int col = nt2 * 16 + (lane & 15);
        w1p[i] = f2bf(W1[k * D1 + col]);
    }
    __syncthreads();
    for (int b = threadIdx.x; b < NBIN; b += 256) binmat[b * NCHUNK + c] = h[b];
}

// ---- per-bin row scan: binmat[b][*] -> exclusive within-row prefix + total ---
__global__ __launch_bounds__(256) void k_binprescan(int* __restrict__ binmat,
                                                    int* __restrict__ binTot) {
    __shared__ int sh[256];
    int b = blockIdx.x, t = threadIdx.x;
    int v = (t < NCHUNK) ? binmat[b * NCHUNK + t] : 0;
    sh[t] = v;
    __syncthreads();
    for (int d = 1; d < 256; d <<= 1) {
        int tv = (t >= d) ? sh[t - d] : 0;
        __syncthreads();
        sh[t] += tv;
        __syncthreads();
    }
    if (t < NCHUNK) binmat[b * NCHUNK + t] = sh[t] - v;   // exclusive in-row
    if (t == 255) binTot[b] = sh[255];
}

// -- GEMM1 via MFMA bf16 + fused al1; blocks >= G1_BLOCKS run binscatter -------
__global__ __launch_bounds__(256) void k_gemm1m(
    const float* __restrict__ x, const unsigned short* __restrict__ w1p,
    const float* __restrict__ a1s, const float* __restrict__ a1d,
    unsigned short* __restrict__ xp1b, float* __restrict__ al1s,
    float* __restrict__ al1d, const int* __restrict__ ei,
    const int* __restrict__ offs, const int* __restrict__ binTot,
    int* __restrict__ binned) {
    __shared__ int cur[NBIN];
    __shared__ int sb[256];
    if (blockIdx.x >= G1_BLOCKS) {
        // ---- binscatter chunk (196 parallel blocks, no serial tail) ----
        int c = blockIdx.x - G1_BLOCKS;
        int t = threadIdx.x;
        int v = (t < NBIN) ? binTot[t] : 0;
        sb[t] = v;
        __syncthreads();
        for (int d = 1; d < 256; d <<= 1) {
            int tv = (t >= d) ? sb[t - d] : 0;
            __syncthreads();
            sb[t] += tv;
            __syncthreads();
        }
        if (t < NBIN) cur[t] = (sb[t] - v) + offs[t * NCHUNK + c];
        __syncthreads();
        int e0 = c * E_CHUNK;
        int e1 = e0 + E_CHUNK; if (e1 > N_EDGES) e1 = N_EDGES;
        for (int e = e0 + t; e < e1; e += 256) {
            int s = ei[e], d = ei[N_EDGES + e];
            int pos = atomicAdd(&cur[d >> 8], 1);
            binned[pos] = s | ((d & 255) << 16);   // src < 65536
        }
        return;
    }
    const int l = threadIdx.x & 63;
    const int wid = threadIdx.x >> 6;
    const int wr = wid >> 1, wc = wid & 1;
    const int l15 = l & 15, l4 = l >> 4;
    const int base = blockIdx.x * 64;
    const int r0 = base + wr * 32;

    f32x4 acc[2][8] = {};
#pragma unroll
    for (int ks = 0; ks < 4; ++ks) {
        const int kk = ks * 32 + l4 * 8;
        short8 af[2];
#pragma unroll
        for (int rt = 0; rt < 2; ++rt) {
            int row = r0 + rt * 16 + l15;
            float4 v0 = make_float4(0.f, 0.f, 0.f, 0.f), v1 = v0;
            if (row < N_NODES) {
                const float* xr = x + (size_t)row * FDIM + kk;
                v0 = *(const float4*)xr;
                v1 = *(const float4*)(xr + 4);
            }
            short8 a;
            a[0] = (short)f2bf(v0.x); a[1] = (short)f2bf(v0.y);
            a[2] = (short)f2bf(v0.z); a[3] = (short)f2bf(v0.w);
            a[4] = (short)f2bf(v1.x); a[5] = (short)f2bf(v1.y);
            a[6] = (short)f2bf(v1.z); a[7] = (short)f2bf(v1.w);
            af[rt] = a;
        }
#pragma unroll
        for (int nt = 0; nt < 8; ++nt) {
            int nt2 = wc * 8 + nt;
            short8 bf_ = *(const short8*)&w1p[(size_t)((ks * 16 + nt2) * 64 + l) * 8];
            acc[0][nt] = __builtin_amdgcn_mfma_f32_16x16x32_bf16(af[0], bf_, acc[0][nt], 0, 0, 0);
            acc[1][nt] = __builtin_amdgcn_mfma_f32_16x16x32_bf16(af[1], bf_, acc[1][nt], 0, 0, 0);
        }
    }
#pragma unroll
    for (int rt = 0; rt < 2; ++rt) {
        int rbase = r0 + rt * 16 + l4 * 4;
#pragma unroll
        for (int nt = 0; nt < 8; ++nt) {
            int col = wc * 128 + nt * 16 + l15;
            f32x4 c = acc[rt][nt];
#pragma unroll
            for (int r = 0; r < 4; ++r) {
                int row = rbase + r;
                if (row < N_NODES) xp1b[(size_t)row * D1 + col] = f2bf(c[r]);
            }
        }
    }
#pragma unroll
    for (int hl = 0; hl < 4; ++hl) {
        int hg = wc * 4 + hl;
        float as0 = a1s[hg * NC + l15], as1 = a1s[hg * NC + 16 + l15];
        float ad0 = a1d[hg * NC + l15], ad1 = a1d[hg * NC + 16 + l15];
#pragma unroll
        for (int rt = 0; rt < 2; ++rt) {
            f32x4 c0 = acc[rt][2 * hl], c1 = acc[rt][2 * hl + 1];
#pragma unroll
            for (int r = 0; r < 4; ++r) {
                float ss = c0[r] * as0 + c1[r] * as1;
                float dd = c0[r] * ad0 + c1[r] * ad1;
#pragma unroll
                for (int msk = 1; msk < 16; msk <<= 1) {
                    ss += __shfl_xor(ss, msk);
                    dd += __shfl_xor(dd, msk);
                }
                int row = r0 + rt * 16 + l4 * 4 + r;
                if (l15 == 0 && row < N_NODES) {
                    al1s[row * NH + hg] = ss;
                    al1d[row * NH + hg] = dd;
                }
            }
        }
    }
}

// ---- per-bin CSR finalize (scan binTot inline) -------------------------------
__global__ __launch_bounds__(256) void k_bincsr(const int* __restrict__ binTot,
                                                const int* __restrict__ binned,
                                                int* __restrict__ rowptr,
                                                int* __restrict__ cnt,
                                                int* __restrict__ esrc) {
    __shared__ int sh[256];
    __shared__ int lcnt[256];
    __shared__ int lcur[256];
    int b = blockIdx.x;
    int t = threadIdx.x;
    int v = (t < NBIN) ? binTot[t] : 0;
    sh[t] = v;
    __syncthreads();
    for (int d = 1; d < 256; d <<= 1) {
        int tv = (t >= d) ? sh[t - d] : 0;
        __syncthreads();
        sh[t] += tv;
        __syncthreads();
    }
    int estart = (b == 0) ? 0 : sh[b - 1];
    int eend = sh[b];
    __syncthreads();
    int nbase = b * 256;
    int nin = N_NODES - nbase; if (nin > 256) nin = 256;
    lcnt[t] = 0;
    __syncthreads();
    for (int e = estart + t; e < eend; e += 256)
        atomicAdd(&lcnt[(binned[e] >> 16) & 255], 1);
    __syncthreads();
    int myc = lcnt[t] + (t < nin ? 1 : 0);   // + self loop
    sh[t] = myc;
    __syncthreads();
    for (int d = 1; d < 256; d <<= 1) {
        int tv = (t >= d) ? sh[t - d] : 0;
        __syncthreads();
        sh[t] += tv;
        __syncthreads();
    }
    int excl = sh[t] - myc;
    int outbase = estart + nbase;            // earlier bins' self-loops = nbase
    int rp = outbase + excl;
    if (t < nin) {
        rowptr[nbase + t] = rp;
        cnt[nbase + t] = myc;
        esrc[rp] = nbase + t;                // self-loop in slot 0
    }
    lcur[t] = rp + (t < nin ? 1 : 0);
    __syncthreads();
    for (int e = estart + t; e < eend; e += 256) {
        int vv = binned[e];
        int pos = atomicAdd(&lcur[(vv >> 16) & 255], 1);
        esrc[pos] = vv & 0xFFFF;
    }
}

// -- attention layer 1 (wave per dst) + FUSED GEMM2/al2 epilogue ---------------
// pass 2: half-wave per edge, 16B/lane u16x8 loads
__global__ __launch_bounds__(256) void k_att1f(
    const unsigned short* __restrict__ xp1b, const float* __restrict__ al1s,
    const float* __restrict__ al1d, const float* __restrict__ b1,
    const float* __restrict__ W2, const float* __restrict__ a2s,
    const float* __restrict__ a2d, const int* __restrict__ rowptr,
    const int* __restrict__ cnt, const int* __restrict__ esrc,
    unsigned short* __restrict__ xp2b, float* __restrict__ al2s,
    float* __restrict__ al2d) {
    __shared__ int s_src[4][64];
    __shared__ float s_alpha[4][64 * 8];   // reused as h[256] after pass 2
    int wv = threadIdx.x >> 6;
    int lane = threadIdx.x & 63;
    int n = blockIdx.x * 4 + wv;          // grid exactly covers 50000 = 12500*4
    int start = rowptr[n];
    int deg = cnt[n];
    int dcap = deg < 64 ? deg : 64;
    int dpad = (dcap + 7) & ~7;
    for (int j = lane; j < dpad; j += 64)
        s_src[wv][j] = (j < dcap) ? esrc[start + j] : n;   // pad with self (hot)
    int npad = (dpad - dcap) * 8;
    if (lane < npad) s_alpha[wv][dcap * 8 + lane] = 0.f;   // zero pad alphas
    // pass 1a: leaky logits into LDS + per-(head,edge-group) max
    int h = lane & 7, eg = lane >> 3;
    float ald = al1d[n * NH + h];
    float m = -1e30f;
    for (int j = eg; j < dcap; j += 8) {
        int s = s_src[wv][j];
        float v = al1s[s * NH + h] + ald;
        v = fmaxf(v, NEG * v);                  // leaky relu (NEG<1)
        s_alpha[wv][j * 8 + h] = v;
        m = fmaxf(m, v);
    }
    if (deg > 64) {
        for (int j = 64 + eg; j < deg; j += 8) {
            int s = esrc[start + j];
            float v = al1s[s * NH + h] + ald;
            m = fmaxf(m, fmaxf(v, NEG * v));
        }
    }
    for (int msk = 8; msk < 64; msk <<= 1) m = fmaxf(m, __shfl_xor(m, msk));
    // pass 1b: single exp per (edge,head); den accumulate; alphas UNNORMALIZED
    float den = 0.f;
    for (int j = eg; j < dcap; j += 8) {
        float e = __expf(s_alpha[wv][j * 8 + h] - m);
        s_alpha[wv][j * 8 + h] = e;
        den += e;
    }
    if (deg > 64) {
        for (int j = 64 + eg; j < deg; j += 8) {
            int s = esrc[start + j];
            float v = al1s[s * NH + h] + ald;
            v = fmaxf(v, NEG * v);
            den += __expf(v - m);
        }
    }
    for (int msk = 8; msk < 64; msk <<= 1) den += __shfl_xor(den, msk);
    // pass 2: half-wave per edge; lane owns 8 channels (16B); 8 edges/batch
    int eh = lane >> 5;
    int l5 = lane & 31;
    int h2 = l5 >> 2;                          // head of channels l5*8..+8
    float rd2 = 1.f / __shfl(den, h2);
    float m2 = __shfl(m, h2);
    const int cbb = l5 << 4;                   // byte offset l5*16
    float acc[8] = {0.f, 0.f, 0.f, 0.f, 0.f, 0.f, 0.f, 0.f};
    for (int j0 = 0; j0 < dpad; j0 += 8) {
        int off[4];
        float aw[4];
#pragma unroll
        for (int k = 0; k < 4; ++k) {
            int e = j0 + eh + 2 * k;
            int s = s_src[wv][e];
            aw[k] = s_alpha[wv][e * 8 + h2];
            off[k] = (s << 9) + cbb;           // s*512B + l5*16B
        }
#pragma unroll
        for (int k = 0; k < 4; ++k) {
            u16x8 xv = *(const u16x8*)((const char*)xp1b + off[k]);
#pragma unroll
            for (int c = 0; c < 8; ++c) acc[c] = fmaf(aw[k], bf2f(xv[c]), acc[c]);
        }
    }
    if (deg > 64) {
        float ald2 = al1d[n * NH + h2];
        for (int j = 64 + eh; j < deg; j += 2) {
            int s = esrc[start + j];
            float v = al1s[s * NH + h2] + ald2;
            v = fmaxf(v, NEG * v);
            float al = __expf(v - m2);          // unnormalized
            u16x8 xv = *(const u16x8*)((const char*)xp1b + (s << 9) + cbb);
#pragma unroll
            for (int c = 0; c < 8; ++c) acc[c] = fmaf(al, bf2f(xv[c]), acc[c]);
        }
    }
#pragma unroll
    for (int c = 0; c < 8; ++c) acc[c] += __shfl_xor(acc[c], 32);
    // epilogue A: lanes 0-31 normalize, bias, ELU -> fp32 h into REUSED s_alpha
    float* h_l = &s_alpha[wv][0];
    if (eh == 0) {
        int cb = l5 << 3;                      // channel base l5*8
        float4 b0 = *(const float4*)(b1 + cb);
        float4 b4 = *(const float4*)(b1 + cb + 4);
        float r0_ = fmaf(acc[0], rd2, b0.x);
        float r1_ = fmaf(acc[1], rd2, b0.y);
        float r2_ = fmaf(acc[2], rd2, b0.z);
        float r3_ = fmaf(acc[3], rd2, b0.w);
        float r4_ = fmaf(acc[4], rd2, b4.x);
        float r5_ = fmaf(acc[5], rd2, b4.y);
        float r6_ = fmaf(acc[6], rd2, b4.z);
        float r7_ = fmaf(acc[7], rd2, b4.w);
        r0_ = r0_ > 0.f ? r0_ : expm1f(r0_);
        r1_ = r1_ > 0.f ? r1_ : expm1f(r1_);
        r2_ = r2_ > 0.f ? r2_ : expm1f(r2_);
        r3_ = r3_ > 0.f ? r3_ : expm1f(r3_);
        r4_ = r4_ > 0.f ? r4_ : expm1f(r4_);
        r5_ = r5_ > 0.f ? r5_ : expm1f(r5_);
        r6_ = r6_ > 0.f ? r6_ : expm1f(r6_);
        r7_ = r7_ > 0.f ? r7_ : expm1f(r7_);
        *(float4*)&h_l[cb]     = make_float4(r0_, r1_, r2_, r3_);
        *(float4*)&h_l[cb + 4] = make_float4(r4_, r5_, r6_, r7_);
    }
    // epilogue B v3: fused GEMM2 (h[256] @ W2[256][16]) + al2 logits.
    {
        int o = lane & 15, q = lane >> 4;
        const float* hq = h_l + q * 4;
        const float* wq = W2 + q * 64 + o;
        float po0 = 0.f, po1 = 0.f, po2 = 0.f, po3 = 0.f;
#pragma unroll
        for (int cc = 0; cc < 16; ++cc) {
            float4 hv = *(const float4*)(hq + cc * 16);
            const float* w = wq + cc * 256;
            po0 = fmaf(hv.x, w[0],  po0);
            po1 = fmaf(hv.y, w[16], po1);
            po2 = fmaf(hv.z, w[32], po2);
            po3 = fmaf(hv.w, w[48], po3);
        }
        float po = (po0 + po1) + (po2 + po3);
        po += __shfl_xor(po, 16);
        po += __shfl_xor(po, 32);              // all lanes: full sum for their o
        float ts = po * a2s[o];
        float td = po * a2d[o];
#pragma unroll
        for (int msk = 1; msk < 16; msk <<= 1) {
            ts += __shfl_xor(ts, msk);
            td += __shfl_xor(td, msk);
        }
        if (lane < 16) xp2b[(size_t)n * NCLS + lane] = f2bf(po);
        if (lane == 0) { al2s[n] = ts; al2d[n] = td; }
    }
}

// -------- attention layer 2 (bf16 xp2 gather, mask-free padded pass 2) --------
__global__ __launch_bounds__(256) void k_att2(
    const unsigned short* __restrict__ xp2b, const float* __restrict__ al2s,
    const float* __restrict__ al2d, const float* __restrict__ b2,
    const int* __restrict__ rowptr, const int* __restrict__ cnt,
    const int* __restrict__ esrc, float* __restrict__ out2) {
    __shared__ int s_src[4][64];
    __shared__ float s_a[4][64];
    int wave = threadIdx.x >> 6;
    int lane = threadIdx.x & 63;
    int n = blockIdx.x * 4 + wave;
    int start = rowptr[n];
    int deg = cnt[n];
    int dcap = deg < 64 ? deg : 64;
    int dpad = (dcap + 7) & ~7;
    for (int j = lane; j < dpad; j += 64)
        s_src[wave][j] = (j < dcap) ? esrc[start + j] : n;
    if (lane < dpad - dcap) s_a[wave][dcap + lane] = 0.f;
    float ald = al2d[n];
    float m = -1e30f;
    for (int j = lane; j < dcap; j += 64) {
        int s = s_src[wave][j];
        float v = al2s[s] + ald;
        v = fmaxf(v, NEG * v);
        s_a[wave][j] = v;
        m = fmaxf(m, v);
    }
    if (deg > 64) {
        for (int j = 64 + lane; j < deg; j += 64) {
            float v = al2s[esrc[start + j]] + ald;
            m = fmaxf(m, fmaxf(v, NEG * v));
        }
    }
    for (int msk = 1; msk < 64; msk <<= 1) m = fmaxf(m, __shfl_xor(m, msk));
    float den = 0.f;
    for (int j = lane; j < dcap; j += 64) {
        float e = __expf(s_a[wave][j] - m);
        s_a[wave][j] = e;
        den += e;
    }
    if (deg > 64) {
        for (int j = 64 + lane; j < deg; j += 64) {
            float v = al2s[esrc[start + j]] + ald;
            v = fmaxf(v, NEG * v);
            den += __expf(v - m);
        }
    }
    for (int msk = 1; msk < 64; msk <<= 1) den += __shfl_xor(den, msk);
    float rden = 1.f / den;
    int c = lane & 15;
    int eg = lane >> 4;                   // 4 edge slots x 16 channels
    float acc = 0.f;
    for (int j0 = 0; j0 < dpad; j0 += 8) {
#pragma unroll
        for (int k = 0; k < 2; ++k) {
            int e = j0 + eg + 4 * k;
            float aw = s_a[wave][e];
            int s = s_src[wave][e];
            acc = fmaf(aw, bf2f(xp2b[(size_t)s * NCLS + c]), acc);
        }
    }
    if (deg > 64) {
        for (int j = 64 + eg; j < deg; j += 4) {
            int s = esrc[start + j];
            float v = al2s[s] + ald;
            v = fmaxf(v, NEG * v);
            acc += __expf(v - m) * bf2f(xp2b[(size_t)s * NCLS + c]);
        }
    }
    acc += __shfl_xor(acc, 16);
    acc += __shfl_xor(acc, 32);
    if (lane < 16) out2[(size_t)n * NCLS + lane] = acc * rden + b2[lane];
}

// ---------------- pooling (LDS pre-aggregation, sorted batch) -----------------
__global__ __launch_bounds__(256) void k_pool(
    const float* __restrict__ out2, const int* __restrict__ batch,
    float* __restrict__ poolS, float* __restrict__ poolC) {
    __shared__ float sacc[NGRP * NCLS];
    __shared__ float scnt[NGRP];
    for (int i = threadIdx.x; i < NGRP * NCLS; i += 256) sacc[i] = 0.f;
    if (threadIdx.x < NGRP) scnt[threadIdx.x] = 0.f;
    __syncthreads();
    int n = blockIdx.x * 256 + threadIdx.x;
    if (n < N_NODES) {
        int g = batch[n];
        atomicAdd(&scnt[g], 1.f);
#pragma unroll
        for (int q = 0; q < 4; ++q) {
            float4 v = *(const float4*)(out2 + (size_t)n * NCLS + q * 4);
            atomicAdd(&sacc[g * NCLS + q * 4 + 0], v.x);
            atomicAdd(&sacc[g * NCLS + q * 4 + 1], v.y);
            atomicAdd(&sacc[g * NCLS + q * 4 + 2], v.z);
            atomicAdd(&sacc[g * NCLS + q * 4 + 3], v.w);
        }
    }
    __syncthreads();
    for (int i = threadIdx.x; i < NGRP * NCLS; i += 256)
        if (sacc[i] != 0.f) atomicAdd(&poolS[i], sacc[i]);
    if (threadIdx.x < NGRP && scnt[threadIdx.x] != 0.f)
        atomicAdd(&poolC[threadIdx.x], scnt[threadIdx.x]);
}

__global__ void k_final(const float* __restrict__ poolS,
                        const float* __restrict__ poolC, float* __restrict__ out) {
    int g = threadIdx.x;
    if (g >= NGRP) return;
    float inv = 1.f / fmaxf(poolC[g], 1.f);
    float v[NCLS];
    float m = -1e30f;
#pragma unroll
    for (int c = 0; c < NCLS; ++c) {
        v[c] = poolS[g * NCLS + c] * inv;
        m = fmaxf(m, v[c]);
    }
    float s = 0.f;
#pragma unroll
    for (int c = 0; c < NCLS; ++c) s += expf(v[c] - m);
    float lse = m + logf(s);
#pragma unroll
    for (int c = 0; c < NCLS; ++c) out[g * NCLS + c] = v[c] - lse;
}

extern "C" void kernel_launch(void* const* d_in, const int* in_sizes, int n_in,
                              void* d_out, int out_size, void* d_ws, size_t ws_size,
                              hipStream_t stream) {
    const float* x    = (const float*)d_in[0];
    const int*   ei   = (const int*)d_in[1];
    const int*   batch = (const int*)d_in[2];
    const float* W1   = (const float*)d_in[3];
    const float* a1s  = (const float*)d_in[4];
    const float* a1d  = (const float*)d_in[5];
    const float* b1   = (const float*)d_in[6];
    const float* W2   = (const float*)d_in[7];
    const float* a2s  = (const float*)d_in[8];
    const float* a2d  = (const float*)d_in[9];
    const float* b2   = (const float*)d_in[10];
    float* out = (float*)d_out;

    float* f = (float*)d_ws;
    float* al1s_ = f;  f += (size_t)N_NODES * NH;
    float* al1d_ = f;  f += (size_t)N_NODES * NH;
    float* al2s_ = f;  f += N_NODES;
    float* al2d_ = f;  f += N_NODES;
    float* out2  = f;  f += (size_t)N_NODES * NCLS;
    float* poolS = f;  f += NGRP * NCLS;
    float* poolC = f;  f += NGRP;
    unsigned short* xp1b = (unsigned short*)f;
    unsigned short* xp2b = xp1b + (size_t)N_NODES * D1;
    unsigned short* w1p  = xp2b + (size_t)N_NODES * NCLS;
    int* binmat  = (int*)(w1p + FDIM * D1);
    int* binTot  = binmat + NBIN * NCHUNK;
    int* binned  = binTot + NBIN;
    int* rowptr  = binned + N_EDGES;
    int* cnt     = rowptr + N_NODES;
    int* esrc    = cnt + N_NODES;

    k_init<<<NB_N, 256, 0, stream>>>(W1, w1p, poolS, poolC, ei, binmat);
    k_binprescan<<<NBIN, 256, 0, stream>>>(binmat, binTot);
    k_gemm1m<<<G1_BLOCKS + NCHUNK, 256, 0, stream>>>(x, w1p, a1s, a1d, xp1b,
                                                     al1s_, al1d_, ei, binmat,
                                                     binTot, binned);
    k_bincsr<<<NBIN, 256, 0, stream>>>(binTot, binned, rowptr, cnt, esrc);
    k_att1f<<<N_NODES / 4, 256, 0, stream>>>(xp1b, al1s_, al1d_, b1, W2, a2s, a2d,
                                             rowptr, cnt, esrc, xp2b, al2s_, al2d_);
    k_att2<<<N_NODES / 4, 256, 0, stream>>>(xp2b, al2s_, al2d_, b2, rowptr, cnt, esrc, out2);
    k_pool<<<NB_N, 256, 0, stream>>>(out2, batch, poolS, poolC);
    k_final<<<1, 64, 0, stream>>>(poolS, poolC, out);
}

// Round 21
// 161.364 us; speedup vs baseline: 1.6791x; 1.0561x over previous
//
#include <hip/hip_runtime.h>
#include <math.h>

#define N_NODES 50000
#define N_EDGES 800000
#define FDIM 128
#define NH 8
#define NC 32
#define D1 256      // NH*NC
#define NCLS 16
#define NGRP 64
#define NEG 0.2f
#define E_TOT (N_EDGES + N_NODES)
#define NB_N 196        // (N_NODES+255)/256
#define G1_BLOCKS 782   // (N_NODES+63)/64
#define E_CHUNK 4096
#define NCHUNK 196      // ceil(800000/4096)
#define NBIN 196        // ceil(50000/256)

typedef __attribute__((ext_vector_type(4))) unsigned short u16x4;
typedef __attribute__((ext_vector_type(8))) unsigned short u16x8;
typedef __attribute__((ext_vector_type(8))) short short8;
typedef __attribute__((ext_vector_type(4))) float f32x4;

static __device__ __forceinline__ float bf2f(unsigned short u) {
    return __uint_as_float(((unsigned int)u) << 16);
}
static __device__ __forceinline__ unsigned short f2bf(float f) {
    unsigned int b = __float_as_uint(f);
    return (unsigned short)((b + 0x7FFFu + ((b >> 16) & 1u)) >> 16);
}
// f32 -> fp8 e4m3 (hardware, OCP on gfx950); returns encoded byte
static __device__ __forceinline__ unsigned char f2fp8(float f) {
    int p = __builtin_amdgcn_cvt_pk_fp8_f32(f, 0.f, 0, false);
    return (unsigned char)(p & 0xFF);
}

// ---- init (pool zero + W1 pack) FUSED with per-chunk bin histogram -----------
__global__ __launch_bounds__(256) void k_init(
    const float* __restrict__ W1, unsigned short* __restrict__ w1p,
    float* __restrict__ poolS, float* __restrict__ poolC,
    const int* __restrict__ ei, int* __restrict__ binmat) {
    __shared__ int h[NBIN];
    int c = blockIdx.x;
    for (int b = threadIdx.x; b < NBIN; b += 256) h[b] = 0;
    __syncthreads();
    int e0 = c * E_CHUNK;
    int e1 = e0 + E_CHUNK; if (e1 > N_EDGES) e1 = N_EDGES;
    for (int e = e0 + threadIdx.x; e < e1; e += 256)
        atomicAdd(&h[ei[N_EDGES + e] >> 8], 1);
    // independent init work while histogram atomics settle
    int i = blockIdx.x * 256 + threadIdx.x;
    if (i < NGRP * NCLS) poolS[i] = 0.f;
    if (i < NGRP) poolC[i] = 0.f;
    if (i < FDIM * D1) {
        int ks = i >> 13;
        int r = i & 8191;
        int nt2 = r >> 9;
        int r2 = r & 511;
        int lane = r2 >> 3, e = r2 & 7;
        int k = ks * 32 + (lane >> 4) * 8 + e;
        int col = nt2 * 16 + (lane & 15);
        w1p[i] = f2bf(W1[k * D1 + col]);
    }
    __syncthreads();
    for (int b = threadIdx.x; b < NBIN; b += 256) binmat[b * NCHUNK + c] = h[b];
}

// ---- per-bin row scan: binmat[b][*] -> exclusive within-row prefix + total ---
__global__ __launch_bounds__(256) void k_binprescan(int* __restrict__ binmat,
                                                    int* __restrict__ binTot) {
    __shared__ int sh[256];
    int b = blockIdx.x, t = threadIdx.x;
    int v = (t < NCHUNK) ? binmat[b * NCHUNK + t] : 0;
    sh[t] = v;
    __syncthreads();
    for (int d = 1; d < 256; d <<= 1) {
        int tv = (t >= d) ? sh[t - d] : 0;
        __syncthreads();
        sh[t] += tv;
        __syncthreads();
    }
    if (t < NCHUNK) binmat[b * NCHUNK + t] = sh[t] - v;   // exclusive in-row
    if (t == 255) binTot[b] = sh[255];
}

// -- GEMM1 via MFMA bf16 + fused al1 (fp32); fp8 feature store; tail=binscatter
__global__ __launch_bounds__(256) void k_gemm1m(
    const float* __restrict__ x, const unsigned short* __restrict__ w1p,
    const float* __restrict__ a1s, const float* __restrict__ a1d,
    unsigned char* __restrict__ xp1f8, float* __restrict__ al1s,
    float* __restrict__ al1d, const int* __restrict__ ei,
    const int* __restrict__ offs, const int* __restrict__ binTot,
    int* __restrict__ binned) {
    __shared__ int cur[NBIN];
    __shared__ int sb[256];
    if (blockIdx.x >= G1_BLOCKS) {
        // ---- binscatter chunk (196 parallel blocks, no serial tail) ----
        int c = blockIdx.x - G1_BLOCKS;
        int t = threadIdx.x;
        int v = (t < NBIN) ? binTot[t] : 0;
        sb[t] = v;
        __syncthreads();
        for (int d = 1; d < 256; d <<= 1) {
            int tv = (t >= d) ? sb[t - d] : 0;
            __syncthreads();
            sb[t] += tv;
            __syncthreads();
        }
        if (t < NBIN) cur[t] = (sb[t] - v) + offs[t * NCHUNK + c];
        __syncthreads();
        int e0 = c * E_CHUNK;
        int e1 = e0 + E_CHUNK; if (e1 > N_EDGES) e1 = N_EDGES;
        for (int e = e0 + t; e < e1; e += 256) {
            int s = ei[e], d = ei[N_EDGES + e];
            int pos = atomicAdd(&cur[d >> 8], 1);
            binned[pos] = s | ((d & 255) << 16);   // src < 65536
        }
        return;
    }
    const int l = threadIdx.x & 63;
    const int wid = threadIdx.x >> 6;
    const int wr = wid >> 1, wc = wid & 1;
    const int l15 = l & 15, l4 = l >> 4;
    const int base = blockIdx.x * 64;
    const int r0 = base + wr * 32;

    f32x4 acc[2][8] = {};
#pragma unroll
    for (int ks = 0; ks < 4; ++ks) {
        const int kk = ks * 32 + l4 * 8;
        short8 af[2];
#pragma unroll
        for (int rt = 0; rt < 2; ++rt) {
            int row = r0 + rt * 16 + l15;
            float4 v0 = make_float4(0.f, 0.f, 0.f, 0.f), v1 = v0;
            if (row < N_NODES) {
                const float* xr = x + (size_t)row * FDIM + kk;
                v0 = *(const float4*)xr;
                v1 = *(const float4*)(xr + 4);
            }
            short8 a;
            a[0] = (short)f2bf(v0.x); a[1] = (short)f2bf(v0.y);
            a[2] = (short)f2bf(v0.z); a[3] = (short)f2bf(v0.w);
            a[4] = (short)f2bf(v1.x); a[5] = (short)f2bf(v1.y);
            a[6] = (short)f2bf(v1.z); a[7] = (short)f2bf(v1.w);
            af[rt] = a;
        }
#pragma unroll
        for (int nt = 0; nt < 8; ++nt) {
            int nt2 = wc * 8 + nt;
            short8 bf_ = *(const short8*)&w1p[(size_t)((ks * 16 + nt2) * 64 + l) * 8];
            acc[0][nt] = __builtin_amdgcn_mfma_f32_16x16x32_bf16(af[0], bf_, acc[0][nt], 0, 0, 0);
            acc[1][nt] = __builtin_amdgcn_mfma_f32_16x16x32_bf16(af[1], bf_, acc[1][nt], 0, 0, 0);
        }
    }
    // epilogue 1: fp8 feature stores (row stride 256B)
#pragma unroll
    for (int rt = 0; rt < 2; ++rt) {
        int rbase = r0 + rt * 16 + l4 * 4;
#pragma unroll
        for (int nt = 0; nt < 8; ++nt) {
            int col = wc * 128 + nt * 16 + l15;
            f32x4 c = acc[rt][nt];
#pragma unroll
            for (int r = 0; r < 4; ++r) {
                int row = rbase + r;
                if (row < N_NODES) xp1f8[(size_t)row * D1 + col] = f2fp8(c[r]);
            }
        }
    }
    // epilogue 2: fused al1s/al1d (fp32, full precision)
#pragma unroll
    for (int hl = 0; hl < 4; ++hl) {
        int hg = wc * 4 + hl;
        float as0 = a1s[hg * NC + l15], as1 = a1s[hg * NC + 16 + l15];
        float ad0 = a1d[hg * NC + l15], ad1 = a1d[hg * NC + 16 + l15];
#pragma unroll
        for (int rt = 0; rt < 2; ++rt) {
            f32x4 c0 = acc[rt][2 * hl], c1 = acc[rt][2 * hl + 1];
#pragma unroll
            for (int r = 0; r < 4; ++r) {
                float ss = c0[r] * as0 + c1[r] * as1;
                float dd = c0[r] * ad0 + c1[r] * ad1;
#pragma unroll
                for (int msk = 1; msk < 16; msk <<= 1) {
                    ss += __shfl_xor(ss, msk);
                    dd += __shfl_xor(dd, msk);
                }
                int row = r0 + rt * 16 + l4 * 4 + r;
                if (l15 == 0 && row < N_NODES) {
                    al1s[row * NH + hg] = ss;
                    al1d[row * NH + hg] = dd;
                }
            }
        }
    }
}

// ---- per-bin CSR finalize (scan binTot inline) -------------------------------
__global__ __launch_bounds__(256) void k_bincsr(const int* __restrict__ binTot,
                                                const int* __restrict__ binned,
                                                int* __restrict__ rowptr,
                                                int* __restrict__ cnt,
                                                int* __restrict__ esrc) {
    __shared__ int sh[256];
    __shared__ int lcnt[256];
    __shared__ int lcur[256];
    int b = blockIdx.x;
    int t = threadIdx.x;
    int v = (t < NBIN) ? binTot[t] : 0;
    sh[t] = v;
    __syncthreads();
    for (int d = 1; d < 256; d <<= 1) {
        int tv = (t >= d) ? sh[t - d] : 0;
        __syncthreads();
        sh[t] += tv;
        __syncthreads();
    }
    int estart = (b == 0) ? 0 : sh[b - 1];
    int eend = sh[b];
    __syncthreads();
    int nbase = b * 256;
    int nin = N_NODES - nbase; if (nin > 256) nin = 256;
    lcnt[t] = 0;
    __syncthreads();
    for (int e = estart + t; e < eend; e += 256)
        atomicAdd(&lcnt[(binned[e] >> 16) & 255], 1);
    __syncthreads();
    int myc = lcnt[t] + (t < nin ? 1 : 0);   // + self loop
    sh[t] = myc;
    __syncthreads();
    for (int d = 1; d < 256; d <<= 1) {
        int tv = (t >= d) ? sh[t - d] : 0;
        __syncthreads();
        sh[t] += tv;
        __syncthreads();
    }
    int excl = sh[t] - myc;
    int outbase = estart + nbase;            // earlier bins' self-loops = nbase
    int rp = outbase + excl;
    if (t < nin) {
        rowptr[nbase + t] = rp;
        cnt[nbase + t] = myc;
        esrc[rp] = nbase + t;                // self-loop in slot 0
    }
    lcur[t] = rp + (t < nin ? 1 : 0);
    __syncthreads();
    for (int e = estart + t; e < eend; e += 256) {
        int vv = binned[e];
        int pos = atomicAdd(&lcur[(vv >> 16) & 255], 1);
        esrc[pos] = vv & 0xFFFF;
    }
}

// -- attention layer 1 (wave per dst) + FUSED GEMM2/al2 epilogue ---------------
// pass 2: half-wave per edge, fp8 features: 8B/lane covers 8 channels
__global__ __launch_bounds__(256) void k_att1f(
    const unsigned char* __restrict__ xp1f8, const float* __restrict__ al1s,
    const float* __restrict__ al1d, const float* __restrict__ b1,
    const float* __restrict__ W2, const float* __restrict__ a2s,
    const float* __restrict__ a2d, const int* __restrict__ rowptr,
    const int* __restrict__ cnt, const int* __restrict__ esrc,
    unsigned short* __restrict__ xp2b, float* __restrict__ al2s,
    float* __restrict__ al2d) {
    __shared__ int s_src[4][64];
    __shared__ float s_alpha[4][64 * 8];   // reused as h[256] after pass 2
    int wv = threadIdx.x >> 6;
    int lane = threadIdx.x & 63;
    int n = blockIdx.x * 4 + wv;          // grid exactly covers 50000 = 12500*4
    int start = rowptr[n];
    int deg = cnt[n];
    int dcap = deg < 64 ? deg : 64;
    int dpad = (dcap + 7) & ~7;
    for (int j = lane; j < dpad; j += 64)
        s_src[wv][j] = (j < dcap) ? esrc[start + j] : n;   // pad with self (hot)
    int npad = (dpad - dcap) * 8;
    if (lane < npad) s_alpha[wv][dcap * 8 + lane] = 0.f;   // zero pad alphas
    // pass 1a: leaky logits into LDS + per-(head,edge-group) max
    int h = lane & 7, eg = lane >> 3;
    float ald = al1d[n * NH + h];
    float m = -1e30f;
    for (int j = eg; j < dcap; j += 8) {
        int s = s_src[wv][j];
        float v = al1s[s * NH + h] + ald;
        v = fmaxf(v, NEG * v);                  // leaky relu (NEG<1)
        s_alpha[wv][j * 8 + h] = v;
        m = fmaxf(m, v);
    }
    if (deg > 64) {
        for (int j = 64 + eg; j < deg; j += 8) {
            int s = esrc[start + j];
            float v = al1s[s * NH + h] + ald;
            m = fmaxf(m, fmaxf(v, NEG * v));
        }
    }
    for (int msk = 8; msk < 64; msk <<= 1) m = fmaxf(m, __shfl_xor(m, msk));
    // pass 1b: single exp per (edge,head); den accumulate; alphas UNNORMALIZED
    float den = 0.f;
    for (int j = eg; j < dcap; j += 8) {
        float e = __expf(s_alpha[wv][j * 8 + h] - m);
        s_alpha[wv][j * 8 + h] = e;
        den += e;
    }
    if (deg > 64) {
        for (int j = 64 + eg; j < deg; j += 8) {
            int s = esrc[start + j];
            float v = al1s[s * NH + h] + ald;
            v = fmaxf(v, NEG * v);
            den += __expf(v - m);
        }
    }
    for (int msk = 8; msk < 64; msk <<= 1) den += __shfl_xor(den, msk);
    // pass 2: half-wave per edge; lane owns 8 channels (8B fp8); 8 edges/batch
    int eh = lane >> 5;
    int l5 = lane & 31;
    int h2 = l5 >> 2;                          // head of channels l5*8..+8
    float rd2 = 1.f / __shfl(den, h2);
    float m2 = __shfl(m, h2);
    const int cbb = l5 << 3;                   // byte offset l5*8 (fp8)
    float acc[8] = {0.f, 0.f, 0.f, 0.f, 0.f, 0.f, 0.f, 0.f};
    for (int j0 = 0; j0 < dpad; j0 += 8) {
        int off[4];
        float aw[4];
#pragma unroll
        for (int k = 0; k < 4; ++k) {
            int e = j0 + eh + 2 * k;
            int s = s_src[wv][e];
            aw[k] = s_alpha[wv][e * 8 + h2];
            off[k] = (s << 8) + cbb;           // s*256B + l5*8B
        }
#pragma unroll
        for (int k = 0; k < 4; ++k) {
            uint2 w = *(const uint2*)(xp1f8 + off[k]);
            acc[0] = fmaf(aw[k], __builtin_amdgcn_cvt_f32_fp8(w.x, 0), acc[0]);
            acc[1] = fmaf(aw[k], __builtin_amdgcn_cvt_f32_fp8(w.x, 1), acc[1]);
            acc[2] = fmaf(aw[k], __builtin_amdgcn_cvt_f32_fp8(w.x, 2), acc[2]);
            acc[3] = fmaf(aw[k], __builtin_amdgcn_cvt_f32_fp8(w.x, 3), acc[3]);
            acc[4] = fmaf(aw[k], __builtin_amdgcn_cvt_f32_fp8(w.y, 0), acc[4]);
            acc[5] = fmaf(aw[k], __builtin_amdgcn_cvt_f32_fp8(w.y, 1), acc[5]);
            acc[6] = fmaf(aw[k], __builtin_amdgcn_cvt_f32_fp8(w.y, 2), acc[6]);
            acc[7] = fmaf(aw[k], __builtin_amdgcn_cvt_f32_fp8(w.y, 3), acc[7]);
        }
    }
    if (deg > 64) {
        float ald2 = al1d[n * NH + h2];
        for (int j = 64 + eh; j < deg; j += 2) {
            int s = esrc[start + j];
            float v = al1s[s * NH + h2] + ald2;
            v = fmaxf(v, NEG * v);
            float al = __expf(v - m2);          // unnormalized
            uint2 w = *(const uint2*)(xp1f8 + (s << 8) + cbb);
            acc[0] = fmaf(al, __builtin_amdgcn_cvt_f32_fp8(w.x, 0), acc[0]);
            acc[1] = fmaf(al, __builtin_amdgcn_cvt_f32_fp8(w.x, 1), acc[1]);
            acc[2] = fmaf(al, __builtin_amdgcn_cvt_f32_fp8(w.x, 2), acc[2]);
            acc[3] = fmaf(al, __builtin_amdgcn_cvt_f32_fp8(w.x, 3), acc[3]);
            acc[4] = fmaf(al, __builtin_amdgcn_cvt_f32_fp8(w.y, 0), acc[4]);
            acc[5] = fmaf(al, __builtin_amdgcn_cvt_f32_fp8(w.y, 1), acc[5]);
            acc[6] = fmaf(al, __builtin_amdgcn_cvt_f32_fp8(w.y, 2), acc[6]);
            acc[7] = fmaf(al, __builtin_amdgcn_cvt_f32_fp8(w.y, 3), acc[7]);
        }
    }
#pragma unroll
    for (int c = 0; c < 8; ++c) acc[c] += __shfl_xor(acc[c], 32);
    // epilogue A: lanes 0-31 normalize, bias, ELU -> fp32 h into REUSED s_alpha
    float* h_l = &s_alpha[wv][0];
    if (eh == 0) {
        int cb = l5 << 3;                      // channel base l5*8
        float4 b0 = *(const float4*)(b1 + cb);
        float4 b4 = *(const float4*)(b1 + cb + 4);
        float r0_ = fmaf(acc[0], rd2, b0.x);
        float r1_ = fmaf(acc[1], rd2, b0.y);
        float r2_ = fmaf(acc[2], rd2, b0.z);
        float r3_ = fmaf(acc[3], rd2, b0.w);
        float r4_ = fmaf(acc[4], rd2, b4.x);
        float r5_ = fmaf(acc[5], rd2, b4.y);
        float r6_ = fmaf(acc[6], rd2, b4.z);
        float r7_ = fmaf(acc[7], rd2, b4.w);
        r0_ = r0_ > 0.f ? r0_ : expm1f(r0_);
        r1_ = r1_ > 0.f ? r1_ : expm1f(r1_);
        r2_ = r2_ > 0.f ? r2_ : expm1f(r2_);
        r3_ = r3_ > 0.f ? r3_ : expm1f(r3_);
        r4_ = r4_ > 0.f ? r4_ : expm1f(r4_);
        r5_ = r5_ > 0.f ? r5_ : expm1f(r5_);
        r6_ = r6_ > 0.f ? r6_ : expm1f(r6_);
        r7_ = r7_ > 0.f ? r7_ : expm1f(r7_);
        *(float4*)&h_l[cb]     = make_float4(r0_, r1_, r2_, r3_);
        *(float4*)&h_l[cb + 4] = make_float4(r4_, r5_, r6_, r7_);
    }
    // epilogue B v3: fused GEMM2 (h[256] @ W2[256][16]) + al2 logits.
    {
        int o = lane & 15, q = lane >> 4;
        const float* hq = h_l + q * 4;
        const float* wq = W2 + q * 64 + o;
        float po0 = 0.f, po1 = 0.f, po2 = 0.f, po3 = 0.f;
#pragma unroll
        for (int cc = 0; cc < 16; ++cc) {
            float4 hv = *(const float4*)(hq + cc * 16);
            const float* w = wq + cc * 256;
            po0 = fmaf(hv.x, w[0],  po0);
            po1 = fmaf(hv.y, w[16], po1);
            po2 = fmaf(hv.z, w[32], po2);
            po3 = fmaf(hv.w, w[48], po3);
        }
        float po = (po0 + po1) + (po2 + po3);
        po += __shfl_xor(po, 16);
        po += __shfl_xor(po, 32);              // all lanes: full sum for their o
        float ts = po * a2s[o];
        float td = po * a2d[o];
#pragma unroll
        for (int msk = 1; msk < 16; msk <<= 1) {
            ts += __shfl_xor(ts, msk);
            td += __shfl_xor(td, msk);
        }
        if (lane < 16) xp2b[(size_t)n * NCLS + lane] = f2bf(po);
        if (lane == 0) { al2s[n] = ts; al2d[n] = td; }
    }
}

// -------- attention layer 2 (bf16 xp2 gather, mask-free padded pass 2) --------
__global__ __launch_bounds__(256) void k_att2(
    const unsigned short* __restrict__ xp2b, const float* __restrict__ al2s,
    const float* __restrict__ al2d, const float* __restrict__ b2,
    const int* __restrict__ rowptr, const int* __restrict__ cnt,
    const int* __restrict__ esrc, float* __restrict__ out2) {
    __shared__ int s_src[4][64];
    __shared__ float s_a[4][64];
    int wave = threadIdx.x >> 6;
    int lane = threadIdx.x & 63;
    int n = blockIdx.x * 4 + wave;
    int start = rowptr[n];
    int deg = cnt[n];
    int dcap = deg < 64 ? deg : 64;
    int dpad = (dcap + 7) & ~7;
    for (int j = lane; j < dpad; j += 64)
        s_src[wave][j] = (j < dcap) ? esrc[start + j] : n;
    if (lane < dpad - dcap) s_a[wave][dcap + lane] = 0.f;
    float ald = al2d[n];
    float m = -1e30f;
    for (int j = lane; j < dcap; j += 64) {
        int s = s_src[wave][j];
        float v = al2s[s] + ald;
        v = fmaxf(v, NEG * v);
        s_a[wave][j] = v;
        m = fmaxf(m, v);
    }
    if (deg > 64) {
        for (int j = 64 + lane; j < deg; j += 64) {
            float v = al2s[esrc[start + j]] + ald;
            m = fmaxf(m, fmaxf(v, NEG * v));
        }
    }
    for (int msk = 1; msk < 64; msk <<= 1) m = fmaxf(m, __shfl_xor(m, msk));
    float den = 0.f;
    for (int j = lane; j < dcap; j += 64) {
        float e = __expf(s_a[wave][j] - m);
        s_a[wave][j] = e;
        den += e;
    }
    if (deg > 64) {
        for (int j = 64 + lane; j < deg; j += 64) {
            float v = al2s[esrc[start + j]] + ald;
            v = fmaxf(v, NEG * v);
            den += __expf(v - m);
        }
    }
    for (int msk = 1; msk < 64; msk <<= 1) den += __shfl_xor(den, msk);
    float rden = 1.f / den;
    int c = lane & 15;
    int eg = lane >> 4;                   // 4 edge slots x 16 channels
    float acc = 0.f;
    for (int j0 = 0; j0 < dpad; j0 += 8) {
#pragma unroll
        for (int k = 0; k < 2; ++k) {
            int e = j0 + eg + 4 * k;
            float aw = s_a[wave][e];
            int s = s_src[wave][e];
            acc = fmaf(aw, bf2f(xp2b[(size_t)s * NCLS + c]), acc);
        }
    }
    if (deg > 64) {
        for (int j = 64 + eg; j < deg; j += 4) {
            int s = esrc[start + j];
            float v = al2s[s] + ald;
            v = fmaxf(v, NEG * v);
            acc += __expf(v - m) * bf2f(xp2b[(size_t)s * NCLS + c]);
        }
    }
    acc += __shfl_xor(acc, 16);
    acc += __shfl_xor(acc, 32);
    if (lane < 16) out2[(size_t)n * NCLS + lane] = acc * rden + b2[lane];
}

// ---------------- pooling (LDS pre-aggregation, sorted batch) -----------------
__global__ __launch_bounds__(256) void k_pool(
    const float* __restrict__ out2, const int* __restrict__ batch,
    float* __restrict__ poolS, float* __restrict__ poolC) {
    __shared__ float sacc[NGRP * NCLS];
    __shared__ float scnt[NGRP];
    for (int i = threadIdx.x; i < NGRP * NCLS; i += 256) sacc[i] = 0.f;
    if (threadIdx.x < NGRP) scnt[threadIdx.x] = 0.f;
    __syncthreads();
    int n = blockIdx.x * 256 + threadIdx.x;
    if (n < N_NODES) {
        int g = batch[n];
        atomicAdd(&scnt[g], 1.f);
#pragma unroll
        for (int q = 0; q < 4; ++q) {
            float4 v = *(const float4*)(out2 + (size_t)n * NCLS + q * 4);
            atomicAdd(&sacc[g * NCLS + q * 4 + 0], v.x);
            atomicAdd(&sacc[g * NCLS + q * 4 + 1], v.y);
            atomicAdd(&sacc[g * NCLS + q * 4 + 2], v.z);
            atomicAdd(&sacc[g * NCLS + q * 4 + 3], v.w);
        }
    }
    __syncthreads();
    for (int i = threadIdx.x; i < NGRP * NCLS; i += 256)
        if (sacc[i] != 0.f) atomicAdd(&poolS[i], sacc[i]);
    if (threadIdx.x < NGRP && scnt[threadIdx.x] != 0.f)
        atomicAdd(&poolC[threadIdx.x], scnt[threadIdx.x]);
}

__global__ void k_final(const float* __restrict__ poolS,
                        const float* __restrict__ poolC, float* __restrict__ out) {
    int g = threadIdx.x;
    if (g >= NGRP) return;
    float inv = 1.f / fmaxf(poolC[g], 1.f);
    float v[NCLS];
    float m = -1e30f;
#pragma unroll
    for (int c = 0; c < NCLS; ++c) {
        v[c] = poolS[g * NCLS + c] * inv;
        m = fmaxf(m, v[c]);
    }
    float s = 0.f;
#pragma unroll
    for (int c = 0; c < NCLS; ++c) s += expf(v[c] - m);
    float lse = m + logf(s);
#pragma unroll
    for (int c = 0; c < NCLS; ++c) out[g * NCLS + c] = v[c] - lse;
}

extern "C" void kernel_launch(void* const* d_in, const int* in_sizes, int n_in,
                              void* d_out, int out_size, void* d_ws, size_t ws_size,
                              hipStream_t stream) {
    const float* x    = (const float*)d_in[0];
    const int*   ei   = (const int*)d_in[1];
    const int*   batch = (const int*)d_in[2];
    const float* W1   = (const float*)d_in[3];
    const float* a1s  = (const float*)d_in[4];
    const float* a1d  = (const float*)d_in[5];
    const float* b1   = (const float*)d_in[6];
    const float* W2   = (const float*)d_in[7];
    const float* a2s  = (const float*)d_in[8];
    const float* a2d  = (const float*)d_in[9];
    const float* b2   = (const float*)d_in[10];
    float* out = (float*)d_out;

    float* f = (float*)d_ws;
    float* al1s_ = f;  f += (size_t)N_NODES * NH;
    float* al1d_ = f;  f += (size_t)N_NODES * NH;
    float* al2s_ = f;  f += N_NODES;
    float* al2d_ = f;  f += N_NODES;
    float* out2  = f;  f += (size_t)N_NODES * NCLS;
    float* poolS = f;  f += NGRP * NCLS;
    float* poolC = f;  f += NGRP;
    unsigned short* xp2b = (unsigned short*)f;
    unsigned short* w1p  = xp2b + (size_t)N_NODES * NCLS;
    unsigned char* xp1f8 = (unsigned char*)(w1p + FDIM * D1);
    int* binmat  = (int*)(xp1f8 + (size_t)N_NODES * D1);
    int* binTot  = binmat + NBIN * NCHUNK;
    int* binned  = binTot + NBIN;
    int* rowptr  = binned + N_EDGES;
    int* cnt     = rowptr + N_NODES;
    int* esrc    = cnt + N_NODES;

    k_init<<<NB_N, 256, 0, stream>>>(W1, w1p, poolS, poolC, ei, binmat);
    k_binprescan<<<NBIN, 256, 0, stream>>>(binmat, binTot);
    k_gemm1m<<<G1_BLOCKS + NCHUNK, 256, 0, stream>>>(x, w1p, a1s, a1d, xp1f8,
                                                     al1s_, al1d_, ei, binmat,
                                                     binTot, binned);
    k_bincsr<<<NBIN, 256, 0, stream>>>(binTot, binned, rowptr, cnt, esrc);
    k_att1f<<<N_NODES / 4, 256, 0, stream>>>(xp1f8, al1s_, al1d_, b1, W2, a2s, a2d,
                                             rowptr, cnt, esrc, xp2b, al2s_, al2d_);
    k_att2<<<N_NODES / 4, 256, 0, stream>>>(xp2b, al2s_, al2d_, b2, rowptr, cnt, esrc, out2);
    k_pool<<<NB_N, 256, 0, stream>>>(out2, batch, poolS, poolC);
    k_final<<<1, 64, 0, stream>>>(poolS, poolC, out);
}

// Round 22
// 159.115 us; speedup vs baseline: 1.7029x; 1.0141x over previous
//
#include <hip/hip_runtime.h>
#include <math.h>

#define N_NODES 50000
#define N_EDGES 800000
#define FDIM 128
#define NH 8
#define NC 32
#define D1 256      // NH*NC
#define NCLS 16
#define NGRP 64
#define NEG 0.2f
#define E_TOT (N_EDGES + N_NODES)
#define NB_N 196        // (N_NODES+255)/256
#define G1_BLOCKS 782   // (N_NODES+63)/64
#define E_CHUNK 4096
#define NCHUNK 196      // ceil(800000/4096)
#define NBIN 196        // ceil(50000/256)

typedef __attribute__((ext_vector_type(4))) unsigned short u16x4;
typedef __attribute__((ext_vector_type(8))) unsigned short u16x8;
typedef __attribute__((ext_vector_type(8))) short short8;
typedef __attribute__((ext_vector_type(4))) float f32x4;
typedef __attribute__((ext_vector_type(2))) float f32x2;

static __device__ __forceinline__ float bf2f(unsigned short u) {
    return __uint_as_float(((unsigned int)u) << 16);
}
static __device__ __forceinline__ unsigned short f2bf(float f) {
    unsigned int b = __float_as_uint(f);
    return (unsigned short)((b + 0x7FFFu + ((b >> 16) & 1u)) >> 16);
}
// f32 -> fp8 e4m3 (hardware, OCP on gfx950); returns encoded byte
static __device__ __forceinline__ unsigned char f2fp8(float f) {
    int p = __builtin_amdgcn_cvt_pk_fp8_f32(f, 0.f, 0, false);
    return (unsigned char)(p & 0xFF);
}

// ---- init (pool zero + W1 pack) FUSED with per-chunk bin histogram -----------
__global__ __launch_bounds__(256) void k_init(
    const float* __restrict__ W1, unsigned short* __restrict__ w1p,
    float* __restrict__ poolS, float* __restrict__ poolC,
    const int* __restrict__ ei, int* __restrict__ binmat) {
    __shared__ int h[NBIN];
    int c = blockIdx.x;
    for (int b = threadIdx.x; b < NBIN; b += 256) h[b] = 0;
    __syncthreads();
    int e0 = c * E_CHUNK;
    int e1 = e0 + E_CHUNK; if (e1 > N_EDGES) e1 = N_EDGES;
    for (int e = e0 + threadIdx.x; e < e1; e += 256)
        atomicAdd(&h[ei[N_EDGES + e] >> 8], 1);
    // independent init work while histogram atomics settle
    int i = blockIdx.x * 256 + threadIdx.x;
    if (i < NGRP * NCLS) poolS[i] = 0.f;
    if (i < NGRP) poolC[i] = 0.f;
    if (i < FDIM * D1) {
        int ks = i >> 13;
        int r = i & 8191;
        int nt2 = r >> 9;
        int r2 = r & 511;
        int lane = r2 >> 3, e = r2 & 7;
        int k = ks * 32 + (lane >> 4) * 8 + e;
        int col = nt2 * 16 + (lane & 15);
        w1p[i] = f2bf(W1[k * D1 + col]);
    }
    __syncthreads();
    for (int b = threadIdx.x; b < NBIN; b += 256) binmat[b * NCHUNK + c] = h[b];
}

// ---- per-bin row scan: binmat[b][*] -> exclusive within-row prefix + total ---
__global__ __launch_bounds__(256) void k_binprescan(int* __restrict__ binmat,
                                                    int* __restrict__ binTot) {
    __shared__ int sh[256];
    int b = blockIdx.x, t = threadIdx.x;
    int v = (t < NCHUNK) ? binmat[b * NCHUNK + t] : 0;
    sh[t] = v;
    __syncthreads();
    for (int d = 1; d < 256; d <<= 1) {
        int tv = (t >= d) ? sh[t - d] : 0;
        __syncthreads();
        sh[t] += tv;
        __syncthreads();
    }
    if (t < NCHUNK) binmat[b * NCHUNK + t] = sh[t] - v;   // exclusive in-row
    if (t == 255) binTot[b] = sh[255];
}

// -- GEMM1 via MFMA bf16 + fused al1 (fp32); fp8 feature store; tail=binscatter
__global__ __launch_bounds__(256) void k_gemm1m(
    const float* __restrict__ x, const unsigned short* __restrict__ w1p,
    const float* __restrict__ a1s, const float* __restrict__ a1d,
    unsigned char* __restrict__ xp1f8, float* __restrict__ al1s,
    float* __restrict__ al1d, const int* __restrict__ ei,
    const int* __restrict__ offs, const int* __restrict__ binTot,
    int* __restrict__ binned) {
    __shared__ int cur[NBIN];
    __shared__ int sb[256];
    if (blockIdx.x >= G1_BLOCKS) {
        // ---- binscatter chunk (196 parallel blocks, no serial tail) ----
        int c = blockIdx.x - G1_BLOCKS;
        int t = threadIdx.x;
        int v = (t < NBIN) ? binTot[t] : 0;
        sb[t] = v;
        __syncthreads();
        for (int d = 1; d < 256; d <<= 1) {
            int tv = (t >= d) ? sb[t - d] : 0;
            __syncthreads();
            sb[t] += tv;
            __syncthreads();
        }
        if (t < NBIN) cur[t] = (sb[t] - v) + offs[t * NCHUNK + c];
        __syncthreads();
        int e0 = c * E_CHUNK;
        int e1 = e0 + E_CHUNK; if (e1 > N_EDGES) e1 = N_EDGES;
        for (int e = e0 + t; e < e1; e += 256) {
            int s = ei[e], d = ei[N_EDGES + e];
            int pos = atomicAdd(&cur[d >> 8], 1);
            binned[pos] = s | ((d & 255) << 16);   // src < 65536
        }
        return;
    }
    const int l = threadIdx.x & 63;
    const int wid = threadIdx.x >> 6;
    const int wr = wid >> 1, wc = wid & 1;
    const int l15 = l & 15, l4 = l >> 4;
    const int base = blockIdx.x * 64;
    const int r0 = base + wr * 32;

    f32x4 acc[2][8] = {};
#pragma unroll
    for (int ks = 0; ks < 4; ++ks) {
        const int kk = ks * 32 + l4 * 8;
        short8 af[2];
#pragma unroll
        for (int rt = 0; rt < 2; ++rt) {
            int row = r0 + rt * 16 + l15;
            float4 v0 = make_float4(0.f, 0.f, 0.f, 0.f), v1 = v0;
            if (row < N_NODES) {
                const float* xr = x + (size_t)row * FDIM + kk;
                v0 = *(const float4*)xr;
                v1 = *(const float4*)(xr + 4);
            }
            short8 a;
            a[0] = (short)f2bf(v0.x); a[1] = (short)f2bf(v0.y);
            a[2] = (short)f2bf(v0.z); a[3] = (short)f2bf(v0.w);
            a[4] = (short)f2bf(v1.x); a[5] = (short)f2bf(v1.y);
            a[6] = (short)f2bf(v1.z); a[7] = (short)f2bf(v1.w);
            af[rt] = a;
        }
#pragma unroll
        for (int nt = 0; nt < 8; ++nt) {
            int nt2 = wc * 8 + nt;
            short8 bf_ = *(const short8*)&w1p[(size_t)((ks * 16 + nt2) * 64 + l) * 8];
            acc[0][nt] = __builtin_amdgcn_mfma_f32_16x16x32_bf16(af[0], bf_, acc[0][nt], 0, 0, 0);
            acc[1][nt] = __builtin_amdgcn_mfma_f32_16x16x32_bf16(af[1], bf_, acc[1][nt], 0, 0, 0);
        }
    }
    // epilogue 1: fp8 feature stores (row stride 256B)
#pragma unroll
    for (int rt = 0; rt < 2; ++rt) {
        int rbase = r0 + rt * 16 + l4 * 4;
#pragma unroll
        for (int nt = 0; nt < 8; ++nt) {
            int col = wc * 128 + nt * 16 + l15;
            f32x4 c = acc[rt][nt];
#pragma unroll
            for (int r = 0; r < 4; ++r) {
                int row = rbase + r;
                if (row < N_NODES) xp1f8[(size_t)row * D1 + col] = f2fp8(c[r]);
            }
        }
    }
    // epilogue 2: fused al1s/al1d (fp32, full precision)
#pragma unroll
    for (int hl = 0; hl < 4; ++hl) {
        int hg = wc * 4 + hl;
        float as0 = a1s[hg * NC + l15], as1 = a1s[hg * NC + 16 + l15];
        float ad0 = a1d[hg * NC + l15], ad1 = a1d[hg * NC + 16 + l15];
#pragma unroll
        for (int rt = 0; rt < 2; ++rt) {
            f32x4 c0 = acc[rt][2 * hl], c1 = acc[rt][2 * hl + 1];
#pragma unroll
            for (int r = 0; r < 4; ++r) {
                float ss = c0[r] * as0 + c1[r] * as1;
                float dd = c0[r] * ad0 + c1[r] * ad1;
#pragma unroll
                for (int msk = 1; msk < 16; msk <<= 1) {
                    ss += __shfl_xor(ss, msk);
                    dd += __shfl_xor(dd, msk);
                }
                int row = r0 + rt * 16 + l4 * 4 + r;
                if (l15 == 0 && row < N_NODES) {
                    al1s[row * NH + hg] = ss;
                    al1d[row * NH + hg] = dd;
                }
            }
        }
    }
}

// ---- per-bin CSR finalize (scan binTot inline) -------------------------------
__global__ __launch_bounds__(256) void k_bincsr(const int* __restrict__ binTot,
                                                const int* __restrict__ binned,
                                                int* __restrict__ rowptr,
                                                int* __restrict__ cnt,
                                                int* __restrict__ esrc) {
    __shared__ int sh[256];
    __shared__ int lcnt[256];
    __shared__ int lcur[256];
    int b = blockIdx.x;
    int t = threadIdx.x;
    int v = (t < NBIN) ? binTot[t] : 0;
    sh[t] = v;
    __syncthreads();
    for (int d = 1; d < 256; d <<= 1) {
        int tv = (t >= d) ? sh[t - d] : 0;
        __syncthreads();
        sh[t] += tv;
        __syncthreads();
    }
    int estart = (b == 0) ? 0 : sh[b - 1];
    int eend = sh[b];
    __syncthreads();
    int nbase = b * 256;
    int nin = N_NODES - nbase; if (nin > 256) nin = 256;
    lcnt[t] = 0;
    __syncthreads();
    for (int e = estart + t; e < eend; e += 256)
        atomicAdd(&lcnt[(binned[e] >> 16) & 255], 1);
    __syncthreads();
    int myc = lcnt[t] + (t < nin ? 1 : 0);   // + self loop
    sh[t] = myc;
    __syncthreads();
    for (int d = 1; d < 256; d <<= 1) {
        int tv = (t >= d) ? sh[t - d] : 0;
        __syncthreads();
        sh[t] += tv;
        __syncthreads();
    }
    int excl = sh[t] - myc;
    int outbase = estart + nbase;            // earlier bins' self-loops = nbase
    int rp = outbase + excl;
    if (t < nin) {
        rowptr[nbase + t] = rp;
        cnt[nbase + t] = myc;
        esrc[rp] = nbase + t;                // self-loop in slot 0
    }
    lcur[t] = rp + (t < nin ? 1 : 0);
    __syncthreads();
    for (int e = estart + t; e < eend; e += 256) {
        int vv = binned[e];
        int pos = atomicAdd(&lcur[(vv >> 16) & 255], 1);
        esrc[pos] = vv & 0xFFFF;
    }
}

// -- attention layer 1 (wave per dst) + FUSED GEMM2/al2 epilogue ---------------
// pass 2: half-wave per edge, fp8 features: 8B/lane, packed pk_f32_fp8 cvt
__global__ __launch_bounds__(256) void k_att1f(
    const unsigned char* __restrict__ xp1f8, const float* __restrict__ al1s,
    const float* __restrict__ al1d, const float* __restrict__ b1,
    const float* __restrict__ W2, const float* __restrict__ a2s,
    const float* __restrict__ a2d, const int* __restrict__ rowptr,
    const int* __restrict__ cnt, const int* __restrict__ esrc,
    unsigned short* __restrict__ xp2b, float* __restrict__ al2s,
    float* __restrict__ al2d) {
    __shared__ int s_src[4][64];
    __shared__ float s_alpha[4][64 * 8];   // reused as h[256] after pass 2
    int wv = threadIdx.x >> 6;
    int lane = threadIdx.x & 63;
    int n = blockIdx.x * 4 + wv;          // grid exactly covers 50000 = 12500*4
    int start = rowptr[n];
    int deg = cnt[n];
    int dcap = deg < 64 ? deg : 64;
    int dpad = (dcap + 7) & ~7;
    for (int j = lane; j < dpad; j += 64)
        s_src[wv][j] = (j < dcap) ? esrc[start + j] : n;   // pad with self (hot)
    int npad = (dpad - dcap) * 8;
    if (lane < npad) s_alpha[wv][dcap * 8 + lane] = 0.f;   // zero pad alphas
    // pass 1a: leaky logits into LDS + per-(head,edge-group) max
    int h = lane & 7, eg = lane >> 3;
    float ald = al1d[n * NH + h];
    float m = -1e30f;
    for (int j = eg; j < dcap; j += 8) {
        int s = s_src[wv][j];
        float v = al1s[s * NH + h] + ald;
        v = fmaxf(v, NEG * v);                  // leaky relu (NEG<1)
        s_alpha[wv][j * 8 + h] = v;
        m = fmaxf(m, v);
    }
    if (deg > 64) {
        for (int j = 64 + eg; j < deg; j += 8) {
            int s = esrc[start + j];
            float v = al1s[s * NH + h] + ald;
            m = fmaxf(m, fmaxf(v, NEG * v));
        }
    }
    for (int msk = 8; msk < 64; msk <<= 1) m = fmaxf(m, __shfl_xor(m, msk));
    // pass 1b: single exp per (edge,head); den accumulate; alphas UNNORMALIZED
    float den = 0.f;
    for (int j = eg; j < dcap; j += 8) {
        float e = __expf(s_alpha[wv][j * 8 + h] - m);
        s_alpha[wv][j * 8 + h] = e;
        den += e;
    }
    if (deg > 64) {
        for (int j = 64 + eg; j < deg; j += 8) {
            int s = esrc[start + j];
            float v = al1s[s * NH + h] + ald;
            v = fmaxf(v, NEG * v);
            den += __expf(v - m);
        }
    }
    for (int msk = 8; msk < 64; msk <<= 1) den += __shfl_xor(den, msk);
    // pass 2: half-wave per edge; lane owns 8 channels (8B fp8); 8 edges/batch
    int eh = lane >> 5;
    int l5 = lane & 31;
    int h2 = l5 >> 2;                          // head of channels l5*8..+8
    float rd2 = 1.f / __shfl(den, h2);
    float m2 = __shfl(m, h2);
    const int cbb = l5 << 3;                   // byte offset l5*8 (fp8)
    float acc[8] = {0.f, 0.f, 0.f, 0.f, 0.f, 0.f, 0.f, 0.f};
    for (int j0 = 0; j0 < dpad; j0 += 8) {
        int off[4];
        float aw[4];
#pragma unroll
        for (int k = 0; k < 4; ++k) {
            int e = j0 + eh + 2 * k;
            int s = s_src[wv][e];
            aw[k] = s_alpha[wv][e * 8 + h2];
            off[k] = (s << 8) + cbb;           // s*256B + l5*8B
        }
#pragma unroll
        for (int k = 0; k < 4; ++k) {
            uint2 w = *(const uint2*)(xp1f8 + off[k]);
            f32x2 p01 = __builtin_amdgcn_cvt_pk_f32_fp8(w.x, false);
            f32x2 p23 = __builtin_amdgcn_cvt_pk_f32_fp8(w.x, true);
            f32x2 p45 = __builtin_amdgcn_cvt_pk_f32_fp8(w.y, false);
            f32x2 p67 = __builtin_amdgcn_cvt_pk_f32_fp8(w.y, true);
            acc[0] = fmaf(aw[k], p01[0], acc[0]);
            acc[1] = fmaf(aw[k], p01[1], acc[1]);
            acc[2] = fmaf(aw[k], p23[0], acc[2]);
            acc[3] = fmaf(aw[k], p23[1], acc[3]);
            acc[4] = fmaf(aw[k], p45[0], acc[4]);
            acc[5] = fmaf(aw[k], p45[1], acc[5]);
            acc[6] = fmaf(aw[k], p67[0], acc[6]);
            acc[7] = fmaf(aw[k], p67[1], acc[7]);
        }
    }
    if (deg > 64) {
        float ald2 = al1d[n * NH + h2];
        for (int j = 64 + eh; j < deg; j += 2) {
            int s = esrc[start + j];
            float v = al1s[s * NH + h2] + ald2;
            v = fmaxf(v, NEG * v);
            float al = __expf(v - m2);          // unnormalized
            uint2 w = *(const uint2*)(xp1f8 + (s << 8) + cbb);
            f32x2 p01 = __builtin_amdgcn_cvt_pk_f32_fp8(w.x, false);
            f32x2 p23 = __builtin_amdgcn_cvt_pk_f32_fp8(w.x, true);
            f32x2 p45 = __builtin_amdgcn_cvt_pk_f32_fp8(w.y, false);
            f32x2 p67 = __builtin_amdgcn_cvt_pk_f32_fp8(w.y, true);
            acc[0] = fmaf(al, p01[0], acc[0]);
            acc[1] = fmaf(al, p01[1], acc[1]);
            acc[2] = fmaf(al, p23[0], acc[2]);
            acc[3] = fmaf(al, p23[1], acc[3]);
            acc[4] = fmaf(al, p45[0], acc[4]);
            acc[5] = fmaf(al, p45[1], acc[5]);
            acc[6] = fmaf(al, p67[0], acc[6]);
            acc[7] = fmaf(al, p67[1], acc[7]);
        }
    }
#pragma unroll
    for (int c = 0; c < 8; ++c) acc[c] += __shfl_xor(acc[c], 32);
    // epilogue A: lanes 0-31 normalize, bias, ELU -> fp32 h into REUSED s_alpha
    float* h_l = &s_alpha[wv][0];
    if (eh == 0) {
        int cb = l5 << 3;                      // channel base l5*8
        float4 b0 = *(const float4*)(b1 + cb);
        float4 b4 = *(const float4*)(b1 + cb + 4);
        float r0_ = fmaf(acc[0], rd2, b0.x);
        float r1_ = fmaf(acc[1], rd2, b0.y);
        float r2_ = fmaf(acc[2], rd2, b0.z);
        float r3_ = fmaf(acc[3], rd2, b0.w);
        float r4_ = fmaf(acc[4], rd2, b4.x);
        float r5_ = fmaf(acc[5], rd2, b4.y);
        float r6_ = fmaf(acc[6], rd2, b4.z);
        float r7_ = fmaf(acc[7], rd2, b4.w);
        r0_ = r0_ > 0.f ? r0_ : expm1f(r0_);
        r1_ = r1_ > 0.f ? r1_ : expm1f(r1_);
        r2_ = r2_ > 0.f ? r2_ : expm1f(r2_);
        r3_ = r3_ > 0.f ? r3_ : expm1f(r3_);
        r4_ = r4_ > 0.f ? r4_ : expm1f(r4_);
        r5_ = r5_ > 0.f ? r5_ : expm1f(r5_);
        r6_ = r6_ > 0.f ? r6_ : expm1f(r6_);
        r7_ = r7_ > 0.f ? r7_ : expm1f(r7_);
        *(float4*)&h_l[cb]     = make_float4(r0_, r1_, r2_, r3_);
        *(float4*)&h_l[cb + 4] = make_float4(r4_, r5_, r6_, r7_);
    }
    // epilogue B v3: fused GEMM2 (h[256] @ W2[256][16]) + al2 logits.
    {
        int o = lane & 15, q = lane >> 4;
        const float* hq = h_l + q * 4;
        const float* wq = W2 + q * 64 + o;
        float po0 = 0.f, po1 = 0.f, po2 = 0.f, po3 = 0.f;
#pragma unroll
        for (int cc = 0; cc < 16; ++cc) {
            float4 hv = *(const float4*)(hq + cc * 16);
            const float* w = wq + cc * 256;
            po0 = fmaf(hv.x, w[0],  po0);
            po1 = fmaf(hv.y, w[16], po1);
            po2 = fmaf(hv.z, w[32], po2);
            po3 = fmaf(hv.w, w[48], po3);
        }
        float po = (po0 + po1) + (po2 + po3);
        po += __shfl_xor(po, 16);
        po += __shfl_xor(po, 32);              // all lanes: full sum for their o
        float ts = po * a2s[o];
        float td = po * a2d[o];
#pragma unroll
        for (int msk = 1; msk < 16; msk <<= 1) {
            ts += __shfl_xor(ts, msk);
            td += __shfl_xor(td, msk);
        }
        if (lane < 16) xp2b[(size_t)n * NCLS + lane] = f2bf(po);
        if (lane == 0) { al2s[n] = ts; al2d[n] = td; }
    }
}

// -------- attention layer 2 (bf16 xp2 gather, mask-free padded pass 2) --------
__global__ __launch_bounds__(256) void k_att2(
    const unsigned short* __restrict__ xp2b, const float* __restrict__ al2s,
    const float* __restrict__ al2d, const float* __restrict__ b2,
    const int* __restrict__ rowptr, const int* __restrict__ cnt,
    const int* __restrict__ esrc, float* __restrict__ out2) {
    __shared__ int s_src[4][64];
    __shared__ float s_a[4][64];
    int wave = threadIdx.x >> 6;
    int lane = threadIdx.x & 63;
    int n = blockIdx.x * 4 + wave;
    int start = rowptr[n];
    int deg = cnt[n];
    int dcap = deg < 64 ? deg : 64;
    int dpad = (dcap + 7) & ~7;
    for (int j = lane; j < dpad; j += 64)
        s_src[wave][j] = (j < dcap) ? esrc[start + j] : n;
    if (lane < dpad - dcap) s_a[wave][dcap + lane] = 0.f;
    float ald = al2d[n];
    float m = -1e30f;
    for (int j = lane; j < dcap; j += 64) {
        int s = s_src[wave][j];
        float v = al2s[s] + ald;
        v = fmaxf(v, NEG * v);
        s_a[wave][j] = v;
        m = fmaxf(m, v);
    }
    if (deg > 64) {
        for (int j = 64 + lane; j < deg; j += 64) {
            float v = al2s[esrc[start + j]] + ald;
            m = fmaxf(m, fmaxf(v, NEG * v));
        }
    }
    for (int msk = 1; msk < 64; msk <<= 1) m = fmaxf(m, __shfl_xor(m, msk));
    float den = 0.f;
    for (int j = lane; j < dcap; j += 64) {
        float e = __expf(s_a[wave][j] - m);
        s_a[wave][j] = e;
        den += e;
    }
    if (deg > 64) {
        for (int j = 64 + lane; j < deg; j += 64) {
            float v = al2s[esrc[start + j]] + ald;
            v = fmaxf(v, NEG * v);
            den += __expf(v - m);
        }
    }
    for (int msk = 1; msk < 64; msk <<= 1) den += __shfl_xor(den, msk);
    float rden = 1.f / den;
    int c = lane & 15;
    int eg = lane >> 4;                   // 4 edge slots x 16 channels
    float acc = 0.f;
    for (int j0 = 0; j0 < dpad; j0 += 8) {
#pragma unroll
        for (int k = 0; k < 2; ++k) {
            int e = j0 + eg + 4 * k;
            float aw = s_a[wave][e];
            int s = s_src[wave][e];
            acc = fmaf(aw, bf2f(xp2b[(size_t)s * NCLS + c]), acc);
        }
    }
    if (deg > 64) {
        for (int j = 64 + eg; j < deg; j += 4) {
            int s = esrc[start + j];
            float v = al2s[s] + ald;
            v = fmaxf(v, NEG * v);
            acc += __expf(v - m) * bf2f(xp2b[(size_t)s * NCLS + c]);
        }
    }
    acc += __shfl_xor(acc, 16);
    acc += __shfl_xor(acc, 32);
    if (lane < 16) out2[(size_t)n * NCLS + lane] = acc * rden + b2[lane];
}

// ---------------- pooling (LDS pre-aggregation, sorted batch) -----------------
__global__ __launch_bounds__(256) void k_pool(
    const float* __restrict__ out2, const int* __restrict__ batch,
    float* __restrict__ poolS, float* __restrict__ poolC) {
    __shared__ float sacc[NGRP * NCLS];
    __shared__ float scnt[NGRP];
    for (int i = threadIdx.x; i < NGRP * NCLS; i += 256) sacc[i] = 0.f;
    if (threadIdx.x < NGRP) scnt[threadIdx.x] = 0.f;
    __syncthreads();
    int n = blockIdx.x * 256 + threadIdx.x;
    if (n < N_NODES) {
        int g = batch[n];
        atomicAdd(&scnt[g], 1.f);
#pragma unroll
        for (int q = 0; q < 4; ++q) {
            float4 v = *(const float4*)(out2 + (size_t)n * NCLS + q * 4);
            atomicAdd(&sacc[g * NCLS + q * 4 + 0], v.x);
            atomicAdd(&sacc[g * NCLS + q * 4 + 1], v.y);
            atomicAdd(&sacc[g * NCLS + q * 4 + 2], v.z);
            atomicAdd(&sacc[g * NCLS + q * 4 + 3], v.w);
        }
    }
    __syncthreads();
    for (int i = threadIdx.x; i < NGRP * NCLS; i += 256)
        if (sacc[i] != 0.f) atomicAdd(&poolS[i], sacc[i]);
    if (threadIdx.x < NGRP && scnt[threadIdx.x] != 0.f)
        atomicAdd(&poolC[threadIdx.x], scnt[threadIdx.x]);
}

__global__ void k_final(const float* __restrict__ poolS,
                        const float* __restrict__ poolC, float* __restrict__ out) {
    int g = threadIdx.x;
    if (g >= NGRP) return;
    float inv = 1.f / fmaxf(poolC[g], 1.f);
    float v[NCLS];
    float m = -1e30f;
#pragma unroll
    for (int c = 0; c < NCLS; ++c) {
        v[c] = poolS[g * NCLS + c] * inv;
        m = fmaxf(m, v[c]);
    }
    float s = 0.f;
#pragma unroll
    for (int c = 0; c < NCLS; ++c) s += expf(v[c] - m);
    float lse = m + logf(s);
#pragma unroll
    for (int c = 0; c < NCLS; ++c) out[g * NCLS + c] = v[c] - lse;
}

extern "C" void kernel_launch(void* const* d_in, const int* in_sizes, int n_in,
                              void* d_out, int out_size, void* d_ws, size_t ws_size,
                              hipStream_t stream) {
    const float* x    = (const float*)d_in[0];
    const int*   ei   = (const int*)d_in[1];
    const int*   batch = (const int*)d_in[2];
    const float* W1   = (const float*)d_in[3];
    const float* a1s  = (const float*)d_in[4];
    const float* a1d  = (const float*)d_in[5];
    const float* b1   = (const float*)d_in[6];
    const float* W2   = (const float*)d_in[7];
    const float* a2s  = (const float*)d_in[8];
    const float* a2d  = (const float*)d_in[9];
    const float* b2   = (const float*)d_in[10];
    float* out = (float*)d_out;

    float* f = (float*)d_ws;
    float* al1s_ = f;  f += (size_t)N_NODES * NH;
    float* al1d_ = f;  f += (size_t)N_NODES * NH;
    float* al2s_ = f;  f += N_NODES;
    float* al2d_ = f;  f += N_NODES;
    float* out2  = f;  f += (size_t)N_NODES * NCLS;
    float* poolS = f;  f += NGRP * NCLS;
    float* poolC = f;  f += NGRP;
    unsigned short* xp2b = (unsigned short*)f;
    unsigned short* w1p  = xp2b + (size_t)N_NODES * NCLS;
    unsigned char* xp1f8 = (unsigned char*)(w1p + FDIM * D1);
    int* binmat  = (int*)(xp1f8 + (size_t)N_NODES * D1);
    int* binTot  = binmat + NBIN * NCHUNK;
    int* binned  = binTot + NBIN;
    int* rowptr  = binned + N_EDGES;
    int* cnt     = rowptr + N_NODES;
    int* esrc    = cnt + N_NODES;

    k_init<<<NB_N, 256, 0, stream>>>(W1, w1p, poolS, poolC, ei, binmat);
    k_binprescan<<<NBIN, 256, 0, stream>>>(binmat, binTot);
    k_gemm1m<<<G1_BLOCKS + NCHUNK, 256, 0, stream>>>(x, w1p, a1s, a1d, xp1f8,
                                                     al1s_, al1d_, ei, binmat,
                                                     binTot, binned);
    k_bincsr<<<NBIN, 256, 0, stream>>>(binTot, binned, rowptr, cnt, esrc);
    k_att1f<<<N_NODES / 4, 256, 0, stream>>>(xp1f8, al1s_, al1d_, b1, W2, a2s, a2d,
                                             rowptr, cnt, esrc, xp2b, al2s_, al2d_);
    k_att2<<<N_NODES / 4, 256, 0, stream>>>(xp2b, al2s_, al2d_, b2, rowptr, cnt, esrc, out2);
    k_pool<<<NB_N, 256, 0, stream>>>(out2, batch, poolS, poolC);
    k_final<<<1, 64, 0, stream>>>(poolS, poolC, out);
}